// Round 16
// baseline (385.470 us; speedup 1.0000x reference)
//
#include <hip/hip_runtime.h>

// GCN 2-layer. Round-15: gemm1 <115us but model says LDS 4-way conflict
// (rotation insufficient: rq*64 = 0 mod 32 banks) + 2 blocks/CU (64KB LDS).
// Fix: per-chunk W staging (2x1KB, no persistent 32KB wt) + row stride 20
// floats (80B = 5x16B: aligned b128, rows spread over 8 bank groups, free).
// LDS 42KB -> 3 blocks/CU, VALU-bound (~42us floor). Also: bktcnt scan_add
// folded into binfill/hist2/fill3 (one less pass).

#define NF 512
#define NH 16
#define NRANGE 32
#define NS2 32
#define RS 3125           // nodes per range = 100000/32
#define EB 1024           // edges per bin block
#define GROWS 256         // gemm rows per block
#define GK 16             // gemm k-chunk (double-buffered)
#define XST 20            // xs row stride (floats): 80B = 5*16B, bank-spread

__global__ __launch_bounds__(256) void k_bincount(const int* __restrict__ dst,
                                                  int* __restrict__ bktcnt,
                                                  int E, int nblk) {
    __shared__ int cnt[NRANGE];
    if (threadIdx.x < NRANGE) cnt[threadIdx.x] = 0;
    __syncthreads();
    int b0 = blockIdx.x * EB;
#pragma unroll
    for (int j = 0; j < 4; ++j) {
        int e = b0 + j * 256 + threadIdx.x;
        if (e < E) atomicAdd(&cnt[dst[e] / RS], 1);
    }
    __syncthreads();
    if (threadIdx.x < NRANGE)
        bktcnt[threadIdx.x * nblk + blockIdx.x] = cnt[threadIdx.x];
}

// exclusive scan (verified rounds 6-15); safe with out==in
__global__ __launch_bounds__(256) void k_scan_block(const int* __restrict__ in,
                                                    int* __restrict__ outp,
                                                    int* __restrict__ bsum, int n) {
    __shared__ int sh[256];
    int t = threadIdx.x, g = blockIdx.x * 256 + t;
    int v = (g < n) ? in[g] : 0;
    sh[t] = v; __syncthreads();
    for (int off = 1; off < 256; off <<= 1) {
        int a = (t >= off) ? sh[t - off] : 0;
        __syncthreads();
        sh[t] += a;
        __syncthreads();
    }
    if (g < n) outp[g] = sh[t] - v;
    if (t == 255) bsum[blockIdx.x] = sh[255];
}

// fused: per-node degree (sum of per-slice partials) + block scan
__global__ __launch_bounds__(256) void k_sumscan(const int* __restrict__ partials,
                                                 int* __restrict__ rowptr,
                                                 int* __restrict__ bsum, int n) {
    __shared__ int sh[256];
    int t = threadIdx.x, g = blockIdx.x * 256 + t;
    int v = 0;
    if (g < n) {
        int r = g / RS, b = g - r * RS;
        const int* p = partials + (size_t)(r * NS2) * RS + b;
#pragma unroll
        for (int s = 0; s < NS2; ++s) v += p[s * RS];
    }
    sh[t] = v; __syncthreads();
    for (int off = 1; off < 256; off <<= 1) {
        int a = (t >= off) ? sh[t - off] : 0;
        __syncthreads();
        sh[t] += a;
        __syncthreads();
    }
    if (g < n) rowptr[g] = sh[t] - v;
    if (t == 255) bsum[blockIdx.x] = sh[255];
}

__global__ __launch_bounds__(512) void k_scan_tops(int* __restrict__ bsum,
                                                   int* __restrict__ outp,
                                                   int nb, int n) {
    __shared__ int sh[512];
    int t = threadIdx.x;
    int v = (t < nb) ? bsum[t] : 0;
    sh[t] = v; __syncthreads();
    for (int off = 1; off < 512; off <<= 1) {
        int a = (t >= off) ? sh[t - off] : 0;
        __syncthreads();
        sh[t] += a;
        __syncthreads();
    }
    if (t < nb) bsum[t] = sh[t] - v;
    if (t == 511) outp[n] = sh[511];
}

__global__ __launch_bounds__(256) void k_scan_add(int* __restrict__ outp,
                                                  const int* __restrict__ bsum, int n) {
    int i = blockIdx.x * 256 + threadIdx.x;
    if (i < n) outp[i] += bsum[i >> 8];
}

// write each edge once into its bucket; bsum2 offset applied inline
__global__ __launch_bounds__(256) void k_binfill(const int* __restrict__ src,
                                                 const int* __restrict__ dst,
                                                 const float* __restrict__ ew,
                                                 const int* __restrict__ bktcnt,
                                                 const int* __restrict__ bsum2,
                                                 int2* __restrict__ bin,
                                                 int E, int nblk) {
    __shared__ int base[NRANGE];
    if (threadIdx.x < NRANGE) {
        int idx = threadIdx.x * nblk + blockIdx.x;
        base[threadIdx.x] = bktcnt[idx] + bsum2[idx >> 8];
    }
    __syncthreads();
    int b0 = blockIdx.x * EB;
#pragma unroll
    for (int j = 0; j < 4; ++j) {
        int e = b0 + j * 256 + threadIdx.x;
        if (e < E) {
            int d = dst[e];
            int r = d / RS;
            int pos = atomicAdd(&base[r], 1);          // LDS only
            bin[pos] = make_int2((src[e] << 12) | (d - r * RS),
                                 __float_as_int(ew[e]));
        }
    }
}

__device__ __forceinline__ int bkt_start(const int* bktcnt, const int* bsum2,
                                         int r, int nblk, int E) {
    if (r >= NRANGE) return E;
    int idx = r * nblk;
    return bktcnt[idx] + bsum2[idx >> 8];
}

// per-(range, slice) LDS histogram; reads only its bucket slice
__global__ __launch_bounds__(256) void k_hist2(const int2* __restrict__ bin,
                                               const int* __restrict__ bktcnt,
                                               const int* __restrict__ bsum2,
                                               int* __restrict__ partials,
                                               int E, int nblk) {
    __shared__ int hist[RS];
    int r = blockIdx.x >> 5, s = blockIdx.x & (NS2 - 1);
    for (int t = threadIdx.x; t < RS; t += 256) hist[t] = 0;
    __syncthreads();
    int b0 = bkt_start(bktcnt, bsum2, r, nblk, E);
    int b1 = bkt_start(bktcnt, bsum2, r + 1, nblk, E);
    int len = b1 - b0, ss = (len + NS2 - 1) / NS2;
    int cs = b0 + s * ss, ce = min(cs + ss, b1);
    for (int j = cs + threadIdx.x; j < ce; j += 256)
        atomicAdd(&hist[bin[j].x & 4095], 1);
    __syncthreads();
    int* pp = partials + (size_t)(r * NS2 + s) * RS;
    for (int t = threadIdx.x; t < RS; t += 256) pp[t] = hist[t];
}

// per-slice counts -> exact slot starts
__global__ __launch_bounds__(256) void k_slicecur(int* __restrict__ partials,
                                                  const int* __restrict__ rowptr, int n) {
    int d = blockIdx.x * 256 + threadIdx.x;
    if (d >= n) return;
    int r = d / RS, b = d - r * RS;
    int* p = partials + (size_t)(r * NS2) * RS + b;
    int run = rowptr[d];
#pragma unroll
    for (int s = 0; s < NS2; ++s) {
        int c = p[s * RS];
        p[s * RS] = run;
        run += c;
    }
}

// place edges at exact csr positions; reads only its bucket slice
__global__ __launch_bounds__(256) void k_fill3(const int2* __restrict__ bin,
                                               const int* __restrict__ bktcnt,
                                               const int* __restrict__ bsum2,
                                               const int* __restrict__ partials,
                                               int2* __restrict__ csr,
                                               int E, int nblk) {
    __shared__ int cur[RS];
    int r = blockIdx.x >> 5, s = blockIdx.x & (NS2 - 1);
    const int* cp = partials + (size_t)(r * NS2 + s) * RS;
    for (int t = threadIdx.x; t < RS; t += 256) cur[t] = cp[t];
    __syncthreads();
    int b0 = bkt_start(bktcnt, bsum2, r, nblk, E);
    int b1 = bkt_start(bktcnt, bsum2, r + 1, nblk, E);
    int len = b1 - b0, ss = (len + NS2 - 1) / NS2;
    int cs = b0 + s * ss, ce = min(cs + ss, b1);
    for (int j = cs + threadIdx.x; j < ce; j += 256) {
        int2 p2 = bin[j];
        int pos = atomicAdd(&cur[p2.x & 4095], 1);    // LDS only
        csr[pos] = make_int2(p2.x >> 12, p2.y);
    }
}

// dinv[d] = rsqrt(1 + sum ew over csr row d)
__global__ __launch_bounds__(256) void k_wdeg(const int2* __restrict__ csr,
                                              const int* __restrict__ rowptr,
                                              float* __restrict__ dinv, int n) {
    int tid = blockIdx.x * 256 + threadIdx.x;
    int d = tid >> 4, f = tid & 15;
    if (d >= n) return;
    int e0 = rowptr[d], e1 = rowptr[d + 1];
    float w = 0.0f;
    for (int j = e0 + f; j < e1; j += 16) w += __int_as_float(csr[j].y);
#pragma unroll
    for (int o = 8; o; o >>= 1) w += __shfl_xor(w, o, 16);
    if (f == 0) dinv[d] = rsqrtf(1.0f + w);
}

// h = x @ W1, double-buffered x AND per-chunk W (no persistent 32KB wt).
// xs stride 20 floats: 16B-aligned b128, rows spread over banks (free).
// LDS 42KB -> 3 blocks/CU; VALU-bound inner loop.
__global__ __launch_bounds__(256) void k_gemm1(const float* __restrict__ x,
                                               const float* __restrict__ w1,
                                               float* __restrict__ h, int n) {
    __shared__ float xs[2][GROWS * XST];   // 2 x 20KB
    __shared__ float wtc[2][GK * NH];      // 2 x 1KB
    int rq = threadIdx.x >> 2;             // 0..63 (row quad)
    int fq = threadIdx.x & 3;              // 0..3  (col quad)
    int base = blockIdx.x * GROWS;
    float4 stage[4];
    float wstage;
#define LOAD_CHUNK(kc)                                                        \
    {                                                                         \
        _Pragma("unroll")                                                     \
        for (int li = 0; li < 4; ++li) {                                      \
            int idx = li * 256 + threadIdx.x;                                 \
            int row = idx >> 2, c4 = idx & 3;                                 \
            int rg = base + row; if (rg > n - 1) rg = n - 1;                  \
            stage[li] = *(const float4*)(x + (size_t)rg * NF + (kc) * GK + c4 * 4); \
        }                                                                     \
        int k = threadIdx.x >> 4, f = threadIdx.x & 15;                       \
        wstage = w1[((kc) * GK + k) * NH + f];                                \
    }
#define WRITE_CHUNK(b)                                                        \
    {                                                                         \
        _Pragma("unroll")                                                     \
        for (int li = 0; li < 4; ++li) {                                      \
            int idx = li * 256 + threadIdx.x;                                 \
            int row = idx >> 2, c4 = idx & 3;                                 \
            float* p = &xs[b][row * XST + c4 * 4];                            \
            p[0] = stage[li].x; p[1] = stage[li].y;                           \
            p[2] = stage[li].z; p[3] = stage[li].w;                           \
        }                                                                     \
        int k = threadIdx.x >> 4, f = threadIdx.x & 15;                       \
        wtc[b][(k >> 2) * 64 + (f << 2) + (k & 3)] = wstage;                  \
    }
    float acc[4][4] = {{0.f}};
    LOAD_CHUNK(0)
    WRITE_CHUNK(0)
    __syncthreads();
    for (int kc = 0; kc < NF / GK; ++kc) {
        if (kc + 1 < NF / GK) { LOAD_CHUNK(kc + 1) }   // in flight over compute
        int b = kc & 1;
#pragma unroll
        for (int k4c = 0; k4c < GK / 4; ++k4c) {
            float4 wf[4];
#pragma unroll
            for (int c = 0; c < 4; ++c)
                wf[c] = *(const float4*)&wtc[b][k4c * 64 + (fq * 4 + c) * 4];
#pragma unroll
            for (int i = 0; i < 4; ++i) {
                int row = rq * 4 + i;
                float4 xv = *(const float4*)&xs[b][row * XST + k4c * 4];
#pragma unroll
                for (int c = 0; c < 4; ++c) {
                    acc[i][c] = fmaf(xv.x, wf[c].x, acc[i][c]);
                    acc[i][c] = fmaf(xv.y, wf[c].y, acc[i][c]);
                    acc[i][c] = fmaf(xv.z, wf[c].z, acc[i][c]);
                    acc[i][c] = fmaf(xv.w, wf[c].w, acc[i][c]);
                }
            }
        }
        if (kc + 1 < NF / GK) {
            __syncthreads();               // all lanes done reading buf b^1
            WRITE_CHUNK((kc + 1) & 1)      // vmcnt drain lands behind compute
            __syncthreads();
        }
    }
#pragma unroll
    for (int i = 0; i < 4; ++i) {
        int r = base + rq * 4 + i;
        if (r < n) {
            float4 o = make_float4(acc[i][0], acc[i][1], acc[i][2], acc[i][3]);
            *(float4*)(h + (size_t)r * NH + fq * 4) = o;
        }
    }
#undef LOAD_CHUNK
#undef WRITE_CHUNK
}

// layer-1 gather with fused bias+relu: out = relu(agg + b1[f])
__global__ __launch_bounds__(256) void k_gather_relu(const float* __restrict__ in,
                                                     const float* __restrict__ dinv,
                                                     const int* __restrict__ rowptr,
                                                     const int2* __restrict__ csr,
                                                     const float* __restrict__ b1,
                                                     float* __restrict__ out, int n) {
    int tid = blockIdx.x * 256 + threadIdx.x;
    int d = tid >> 4, f = tid & 15;
    if (d >= n) return;
    float di = dinv[d];
    float acc = in[tid] * di * di;
    int e0 = rowptr[d], e1 = rowptr[d + 1];
    for (int j = e0; j < e1; ++j) {
        int2 ent = csr[j];
        float nrm = dinv[ent.x] * __int_as_float(ent.y) * di;
        acc = fmaf(in[ent.x * NH + f], nrm, acc);
    }
    out[tid] = fmaxf(acc + b1[f], 0.0f);
}

// layer-2 gather (plain)
__global__ __launch_bounds__(256) void k_gather(const float* __restrict__ in,
                                                const float* __restrict__ dinv,
                                                const int* __restrict__ rowptr,
                                                const int2* __restrict__ csr,
                                                float* __restrict__ out, int n) {
    int tid = blockIdx.x * 256 + threadIdx.x;
    int d = tid >> 4, f = tid & 15;
    if (d >= n) return;
    float di = dinv[d];
    float acc = in[tid] * di * di;
    int e0 = rowptr[d], e1 = rowptr[d + 1];
    for (int j = e0; j < e1; ++j) {
        int2 ent = csr[j];
        float nrm = dinv[ent.x] * __int_as_float(ent.y) * di;
        acc = fmaf(in[ent.x * NH + f], nrm, acc);
    }
    out[tid] = acc;
}

__global__ __launch_bounds__(256) void k_out(const float* __restrict__ agg,
                                             const float* __restrict__ w2,
                                             const float* __restrict__ b2,
                                             float* __restrict__ out, int n) {
    __shared__ float w2s[NH * 40];
    __shared__ float b2s[40];
    for (int t = threadIdx.x; t < NH * 40; t += 256) w2s[t] = w2[t];
    if (threadIdx.x < 40) b2s[threadIdx.x] = b2[threadIdx.x];
    __syncthreads();
    int i = blockIdx.x * 256 + threadIdx.x;
    if (i >= n) return;
    float v[NH];
    const float4* ap = (const float4*)(agg + (size_t)i * NH);
#pragma unroll
    for (int m = 0; m < 4; ++m) {
        float4 t4 = ap[m];
        v[4 * m] = t4.x; v[4 * m + 1] = t4.y; v[4 * m + 2] = t4.z; v[4 * m + 3] = t4.w;
    }
    float z[40];
#pragma unroll
    for (int c = 0; c < 40; ++c) {
        float a = b2s[c];
#pragma unroll
        for (int ff = 0; ff < NH; ++ff) a = fmaf(v[ff], w2s[ff * 40 + c], a);
        z[c] = a;
    }
    float mx = z[0];
#pragma unroll
    for (int c = 1; c < 40; ++c) mx = fmaxf(mx, z[c]);
    float sum = 0.0f;
#pragma unroll
    for (int c = 0; c < 40; ++c) sum += expf(z[c] - mx);
    float ls = mx + logf(sum);
    float4* op = (float4*)(out + (size_t)i * 40);
#pragma unroll
    for (int m = 0; m < 10; ++m) {
        float4 o;
        o.x = z[4 * m] - ls; o.y = z[4 * m + 1] - ls;
        o.z = z[4 * m + 2] - ls; o.w = z[4 * m + 3] - ls;
        op[m] = o;
    }
}

extern "C" void kernel_launch(void* const* d_in, const int* in_sizes, int n_in,
                              void* d_out, int out_size, void* d_ws, size_t ws_size,
                              hipStream_t stream) {
    const float* x  = (const float*)d_in[0];
    const int*   ei = (const int*)d_in[1];
    const float* ew = (const float*)d_in[2];
    const float* w1 = (const float*)d_in[3];
    const float* b1 = (const float*)d_in[4];
    const float* w2 = (const float*)d_in[5];
    const float* b2 = (const float*)d_in[6];
    float* out = (float*)d_out;

    int n = in_sizes[0] / NF;      // 100000 (= NRANGE*RS)
    int E = in_sizes[2];           // 3200000
    const int* src = ei;
    const int* dst = ei + E;

    float* ws       = (float*)d_ws;
    float* dinv     = ws;                       // n
    int*   bsum     = (int*)(ws + 200000);      // 1024
    int*   rowptr   = (int*)(ws + 201024);      // n+1
    int*   bsum2    = (int*)(ws + 301056);      // 1024
    int*   bktcnt   = (int*)(ws + 302080);      // 100032, scanned in place
    int*   partials = (int*)(ws + 402112);      // NRANGE*NS2*RS = 3.2M
    int2*  csr      = (int2*)(ws + 3602112);    // 2*E ints
    int2*  bin      = (int2*)(ws + 10002112);   // 2*E ints, dead after fill3
    float* h        = ws + 10002112;            // overlays bin
    float* o1       = ws + 11602112;            // overlays bin

    int nblk  = (E + EB - 1) / EB;              // 3125 bin blocks
    int ncnt  = NRANGE * nblk;                  // 100000 counts
    int nb_c  = (ncnt + 255) / 256;             // 391
    int nb_n  = (n + 255) / 256;                // 391
    int nb_nf = (n * NH + 255) / 256;           // 6250
    int nb_g  = (n + GROWS - 1) / GROWS;        // 391 gemm blocks

    // 1) bin counts + bases (scan in place; block offsets applied inline later)
    k_bincount<<<nblk, 256, 0, stream>>>(dst, bktcnt, E, nblk);
    k_scan_block<<<nb_c, 256, 0, stream>>>(bktcnt, bktcnt, bsum2, ncnt);
    k_scan_tops<<<1, 512, 0, stream>>>(bsum2, bktcnt, nb_c, ncnt);
    // 2) bin edges (each edge written once, single int2 scatter)
    k_binfill<<<nblk, 256, 0, stream>>>(src, dst, ew, bktcnt, bsum2, bin, E, nblk);
    // 3) per-range hist -> rowptr -> exact CSR
    k_hist2<<<NRANGE * NS2, 256, 0, stream>>>(bin, bktcnt, bsum2, partials, E, nblk);
    k_sumscan<<<nb_n, 256, 0, stream>>>(partials, rowptr, bsum, n);
    k_scan_tops<<<1, 512, 0, stream>>>(bsum, rowptr, nb_n, n);
    k_scan_add<<<nb_n, 256, 0, stream>>>(rowptr, bsum, n);
    k_slicecur<<<nb_n, 256, 0, stream>>>(partials, rowptr, n);
    k_fill3<<<NRANGE * NS2, 256, 0, stream>>>(bin, bktcnt, bsum2, partials, csr, E, nblk);
    // 4) GCN pipeline
    k_wdeg<<<nb_nf, 256, 0, stream>>>(csr, rowptr, dinv, n);
    k_gemm1<<<nb_g, 256, 0, stream>>>(x, w1, h, n);
    k_gather_relu<<<nb_nf, 256, 0, stream>>>(h, dinv, rowptr, csr, b1, o1, n);
    k_gather<<<nb_nf, 256, 0, stream>>>(o1, dinv, rowptr, csr, h, n);
    k_out<<<nb_n, 256, 0, stream>>>(h, w2, b2, out, n);
}

// Round 17
// 377.252 us; speedup vs baseline: 1.0218x; 1.0218x over previous
//
#include <hip/hip_runtime.h>

// GCN 2-layer. Round-16 post-mortem: per-chunk W staging regressed (+12us)
// -> gemm1 reverted to the 373us-measured variant (persistent wt + dbuf xs).
// New: 15-bit fixed-point nrm precomputed into a 4B CSR during fill3
// (dinv known early by folding weight-sums into hist2/sumscan; k_wdeg
// deleted). Gathers: pure 4B csr stream + one 64B gather/edge, no per-edge
// dinv fetches. Quant err <= 3e-3 (deg<=~70) vs 8.2e-2 threshold.

#define NF 512
#define NH 16
#define NRANGE 32
#define NS2 32
#define RS 3125           // nodes per range = 100000/32
#define EB 1024           // edges per bin block
#define GROWS 256         // gemm rows per block
#define GK 16             // gemm k-chunk (double-buffered)

// ---- ws layout (4B units) ----
// dinv @0 (100000) | bsum @200000 (1024) | rowptr @201024 (100001)
// bsum2 @301056 (1024) | bktcnt @302080 (100032)
// partials @402112 (3.2M int) | wpartials @3602112 (3.2M float)
// csr uint @6802112 (E) | bin int2 @10002112 (2E, dead after fill3)
// h @10002112 overlays bin | o1 @11602112 overlays bin

__global__ __launch_bounds__(256) void k_bincount(const int* __restrict__ dst,
                                                  int* __restrict__ bktcnt,
                                                  int E, int nblk) {
    __shared__ int cnt[NRANGE];
    if (threadIdx.x < NRANGE) cnt[threadIdx.x] = 0;
    __syncthreads();
    int b0 = blockIdx.x * EB;
#pragma unroll
    for (int j = 0; j < 4; ++j) {
        int e = b0 + j * 256 + threadIdx.x;
        if (e < E) atomicAdd(&cnt[dst[e] / RS], 1);
    }
    __syncthreads();
    if (threadIdx.x < NRANGE)
        bktcnt[threadIdx.x * nblk + blockIdx.x] = cnt[threadIdx.x];
}

// exclusive scan (verified rounds 6-16); safe with out==in
__global__ __launch_bounds__(256) void k_scan_block(const int* __restrict__ in,
                                                    int* __restrict__ outp,
                                                    int* __restrict__ bsum, int n) {
    __shared__ int sh[256];
    int t = threadIdx.x, g = blockIdx.x * 256 + t;
    int v = (g < n) ? in[g] : 0;
    sh[t] = v; __syncthreads();
    for (int off = 1; off < 256; off <<= 1) {
        int a = (t >= off) ? sh[t - off] : 0;
        __syncthreads();
        sh[t] += a;
        __syncthreads();
    }
    if (g < n) outp[g] = sh[t] - v;
    if (t == 255) bsum[blockIdx.x] = sh[255];
}

// fused: per-node degree+weight reduction, dinv write, block scan of counts
__global__ __launch_bounds__(256) void k_sumscan(const int* __restrict__ partials,
                                                 const float* __restrict__ wpartials,
                                                 int* __restrict__ rowptr,
                                                 int* __restrict__ bsum,
                                                 float* __restrict__ dinv, int n) {
    __shared__ int sh[256];
    int t = threadIdx.x, g = blockIdx.x * 256 + t;
    int v = 0;
    if (g < n) {
        int r = g / RS, b = g - r * RS;
        size_t o = (size_t)(r * NS2) * RS + b;
        const int* p = partials + o;
        const float* wp = wpartials + o;
        float w = 1.0f;
#pragma unroll
        for (int s = 0; s < NS2; ++s) { v += p[s * RS]; w += wp[s * RS]; }
        dinv[g] = rsqrtf(w);
    }
    sh[t] = v; __syncthreads();
    for (int off = 1; off < 256; off <<= 1) {
        int a = (t >= off) ? sh[t - off] : 0;
        __syncthreads();
        sh[t] += a;
        __syncthreads();
    }
    if (g < n) rowptr[g] = sh[t] - v;
    if (t == 255) bsum[blockIdx.x] = sh[255];
}

__global__ __launch_bounds__(512) void k_scan_tops(int* __restrict__ bsum,
                                                   int* __restrict__ outp,
                                                   int nb, int n) {
    __shared__ int sh[512];
    int t = threadIdx.x;
    int v = (t < nb) ? bsum[t] : 0;
    sh[t] = v; __syncthreads();
    for (int off = 1; off < 512; off <<= 1) {
        int a = (t >= off) ? sh[t - off] : 0;
        __syncthreads();
        sh[t] += a;
        __syncthreads();
    }
    if (t < nb) bsum[t] = sh[t] - v;
    if (t == 511) outp[n] = sh[511];
}

__global__ __launch_bounds__(256) void k_scan_add(int* __restrict__ outp,
                                                  const int* __restrict__ bsum, int n) {
    int i = blockIdx.x * 256 + threadIdx.x;
    if (i < n) outp[i] += bsum[i >> 8];
}

// write each edge once into its bucket; bsum2 offset applied inline
__global__ __launch_bounds__(256) void k_binfill(const int* __restrict__ src,
                                                 const int* __restrict__ dst,
                                                 const float* __restrict__ ew,
                                                 const int* __restrict__ bktcnt,
                                                 const int* __restrict__ bsum2,
                                                 int2* __restrict__ bin,
                                                 int E, int nblk) {
    __shared__ int base[NRANGE];
    if (threadIdx.x < NRANGE) {
        int idx = threadIdx.x * nblk + blockIdx.x;
        base[threadIdx.x] = bktcnt[idx] + bsum2[idx >> 8];
    }
    __syncthreads();
    int b0 = blockIdx.x * EB;
#pragma unroll
    for (int j = 0; j < 4; ++j) {
        int e = b0 + j * 256 + threadIdx.x;
        if (e < E) {
            int d = dst[e];
            int r = d / RS;
            int pos = atomicAdd(&base[r], 1);          // LDS only
            bin[pos] = make_int2((src[e] << 12) | (d - r * RS),
                                 __float_as_int(ew[e]));
        }
    }
}

__device__ __forceinline__ int bkt_start(const int* bktcnt, const int* bsum2,
                                         int r, int nblk, int E) {
    if (r >= NRANGE) return E;
    int idx = r * nblk;
    return bktcnt[idx] + bsum2[idx >> 8];
}

// per-(range, slice) LDS histogram of counts AND edge-weight sums
__global__ __launch_bounds__(256) void k_hist2(const int2* __restrict__ bin,
                                               const int* __restrict__ bktcnt,
                                               const int* __restrict__ bsum2,
                                               int* __restrict__ partials,
                                               float* __restrict__ wpartials,
                                               int E, int nblk) {
    __shared__ int hist[RS];
    __shared__ float whist[RS];
    int r = blockIdx.x >> 5, s = blockIdx.x & (NS2 - 1);
    for (int t = threadIdx.x; t < RS; t += 256) { hist[t] = 0; whist[t] = 0.f; }
    __syncthreads();
    int b0 = bkt_start(bktcnt, bsum2, r, nblk, E);
    int b1 = bkt_start(bktcnt, bsum2, r + 1, nblk, E);
    int len = b1 - b0, ss = (len + NS2 - 1) / NS2;
    int cs = b0 + s * ss, ce = min(cs + ss, b1);
    for (int j = cs + threadIdx.x; j < ce; j += 256) {
        int2 p2 = bin[j];
        int dl = p2.x & 4095;
        atomicAdd(&hist[dl], 1);
        atomicAdd(&whist[dl], __int_as_float(p2.y));
    }
    __syncthreads();
    size_t o = (size_t)(r * NS2 + s) * RS;
    int* pp = partials + o;
    float* wpp = wpartials + o;
    for (int t = threadIdx.x; t < RS; t += 256) { pp[t] = hist[t]; wpp[t] = whist[t]; }
}

// per-slice counts -> exact slot starts
__global__ __launch_bounds__(256) void k_slicecur(int* __restrict__ partials,
                                                  const int* __restrict__ rowptr, int n) {
    int d = blockIdx.x * 256 + threadIdx.x;
    if (d >= n) return;
    int r = d / RS, b = d - r * RS;
    int* p = partials + (size_t)(r * NS2) * RS + b;
    int run = rowptr[d];
#pragma unroll
    for (int s = 0; s < NS2; ++s) {
        int c = p[s * RS];
        p[s * RS] = run;
        run += c;
    }
}

// place edges: csr = (src<<15) | fixed15(dinv[s]*ew*dinv[d])
__global__ __launch_bounds__(256) void k_fill3(const int2* __restrict__ bin,
                                               const int* __restrict__ bktcnt,
                                               const int* __restrict__ bsum2,
                                               const int* __restrict__ partials,
                                               const float* __restrict__ dinv,
                                               unsigned* __restrict__ csr,
                                               int E, int nblk) {
    __shared__ int cur[RS];
    __shared__ float dv[RS];
    int r = blockIdx.x >> 5, s = blockIdx.x & (NS2 - 1);
    const int* cp = partials + (size_t)(r * NS2 + s) * RS;
    for (int t = threadIdx.x; t < RS; t += 256) {
        cur[t] = cp[t];
        dv[t] = dinv[r * RS + t];
    }
    __syncthreads();
    int b0 = bkt_start(bktcnt, bsum2, r, nblk, E);
    int b1 = bkt_start(bktcnt, bsum2, r + 1, nblk, E);
    int len = b1 - b0, ss = (len + NS2 - 1) / NS2;
    int cs = b0 + s * ss, ce = min(cs + ss, b1);
    for (int j = cs + threadIdx.x; j < ce; j += 256) {
        int2 p2 = bin[j];
        int dl = p2.x & 4095;
        int sn = p2.x >> 12;
        float nrm = dinv[sn] * __int_as_float(p2.y) * dv[dl];
        unsigned w15 = (unsigned)(nrm * 32767.0f + 0.5f);
        int pos = atomicAdd(&cur[dl], 1);             // LDS only
        csr[pos] = ((unsigned)sn << 15) | w15;
    }
}

// h = x @ W1 (round-15-measured variant: persistent wt + dbuf xs, GK=16)
__global__ __launch_bounds__(256) void k_gemm1(const float* __restrict__ x,
                                               const float* __restrict__ w1,
                                               float* __restrict__ h, int n) {
    __shared__ float wt[NF * NH];          // 32KB, read-only after init
    __shared__ float xs[2][GROWS * GK];    // 2 x 16KB
    for (int t = threadIdx.x; t < NF * NH; t += 256) {
        int k = t >> 4, f = t & 15;
        wt[(k >> 2) * 64 + (f << 2) + (k & 3)] = w1[t];
    }
    int rq = threadIdx.x >> 2;             // 0..63 (row quad)
    int fq = threadIdx.x & 3;              // 0..3  (col quad)
    int base = blockIdx.x * GROWS;
    float4 stage[4];
#define LOAD_CHUNK(kc)                                                        \
    _Pragma("unroll")                                                         \
    for (int li = 0; li < 4; ++li) {                                          \
        int idx = li * 256 + threadIdx.x;                                     \
        int row = idx >> 2, c4 = idx & 3;                                     \
        int rg = base + row; if (rg > n - 1) rg = n - 1;                      \
        stage[li] = *(const float4*)(x + (size_t)rg * NF + (kc) * GK + c4 * 4);\
    }
#define WRITE_CHUNK(b)                                                        \
    _Pragma("unroll")                                                         \
    for (int li = 0; li < 4; ++li) {                                          \
        int idx = li * 256 + threadIdx.x;                                     \
        int row = idx >> 2, c4 = idx & 3;                                     \
        int slot = (c4 + (row >> 2)) & 3;                                     \
        float* p = &xs[b][row * GK + slot * 4];                               \
        p[0] = stage[li].x; p[1] = stage[li].y;                               \
        p[2] = stage[li].z; p[3] = stage[li].w;                               \
    }
    float acc[4][4] = {{0.f}};
    LOAD_CHUNK(0)
    WRITE_CHUNK(0)
    __syncthreads();                       // also covers wt
    for (int kc = 0; kc < NF / GK; ++kc) {
        if (kc + 1 < NF / GK) { LOAD_CHUNK(kc + 1) }   // in flight over compute
        int b = kc & 1;
#pragma unroll
        for (int k4c = 0; k4c < GK / 4; ++k4c) {
            int k4 = kc * (GK / 4) + k4c;
            float4 wf[4];
#pragma unroll
            for (int c = 0; c < 4; ++c)
                wf[c] = *(const float4*)&wt[k4 * 64 + (fq * 4 + c) * 4];
#pragma unroll
            for (int i = 0; i < 4; ++i) {
                int row = rq * 4 + i;
                int slot = (k4c + rq) & 3;
                float4 xv = *(const float4*)&xs[b][row * GK + slot * 4];
#pragma unroll
                for (int c = 0; c < 4; ++c) {
                    acc[i][c] = fmaf(xv.x, wf[c].x, acc[i][c]);
                    acc[i][c] = fmaf(xv.y, wf[c].y, acc[i][c]);
                    acc[i][c] = fmaf(xv.z, wf[c].z, acc[i][c]);
                    acc[i][c] = fmaf(xv.w, wf[c].w, acc[i][c]);
                }
            }
        }
        if (kc + 1 < NF / GK) {
            __syncthreads();               // all lanes done with buf b^1 reads
            WRITE_CHUNK((kc + 1) & 1)      // drains vmcnt here, behind compute
            __syncthreads();               // writes visible for next chunk
        }
    }
#pragma unroll
    for (int i = 0; i < 4; ++i) {
        int r = base + rq * 4 + i;
        if (r < n) {
            float4 o = make_float4(acc[i][0], acc[i][1], acc[i][2], acc[i][3]);
            *(float4*)(h + (size_t)r * NH + fq * 4) = o;
        }
    }
#undef LOAD_CHUNK
#undef WRITE_CHUNK
}

// layer-1 gather + fused bias/relu; nrm baked into csr (15-bit fixed)
__global__ __launch_bounds__(256) void k_gather_relu(const float* __restrict__ in,
                                                     const float* __restrict__ dinv,
                                                     const int* __restrict__ rowptr,
                                                     const unsigned* __restrict__ csr,
                                                     const float* __restrict__ b1,
                                                     float* __restrict__ out, int n) {
    int tid = blockIdx.x * 256 + threadIdx.x;
    int d = tid >> 4, f = tid & 15;
    if (d >= n) return;
    float di = dinv[d];
    float acc = in[tid] * di * di;
    int e0 = rowptr[d], e1 = rowptr[d + 1];
    for (int j = e0; j < e1; ++j) {
        unsigned e = csr[j];                          // 4B broadcast
        float nrm = (float)(e & 32767u) * (1.0f / 32767.0f);
        acc = fmaf(in[(e >> 15) * NH + f], nrm, acc);
    }
    out[tid] = fmaxf(acc + b1[f], 0.0f);
}

// layer-2 gather (plain)
__global__ __launch_bounds__(256) void k_gather(const float* __restrict__ in,
                                                const float* __restrict__ dinv,
                                                const int* __restrict__ rowptr,
                                                const unsigned* __restrict__ csr,
                                                float* __restrict__ out, int n) {
    int tid = blockIdx.x * 256 + threadIdx.x;
    int d = tid >> 4, f = tid & 15;
    if (d >= n) return;
    float di = dinv[d];
    float acc = in[tid] * di * di;
    int e0 = rowptr[d], e1 = rowptr[d + 1];
    for (int j = e0; j < e1; ++j) {
        unsigned e = csr[j];
        float nrm = (float)(e & 32767u) * (1.0f / 32767.0f);
        acc = fmaf(in[(e >> 15) * NH + f], nrm, acc);
    }
    out[tid] = acc;
}

__global__ __launch_bounds__(256) void k_out(const float* __restrict__ agg,
                                             const float* __restrict__ w2,
                                             const float* __restrict__ b2,
                                             float* __restrict__ out, int n) {
    __shared__ float w2s[NH * 40];
    __shared__ float b2s[40];
    for (int t = threadIdx.x; t < NH * 40; t += 256) w2s[t] = w2[t];
    if (threadIdx.x < 40) b2s[threadIdx.x] = b2[threadIdx.x];
    __syncthreads();
    int i = blockIdx.x * 256 + threadIdx.x;
    if (i >= n) return;
    float v[NH];
    const float4* ap = (const float4*)(agg + (size_t)i * NH);
#pragma unroll
    for (int m = 0; m < 4; ++m) {
        float4 t4 = ap[m];
        v[4 * m] = t4.x; v[4 * m + 1] = t4.y; v[4 * m + 2] = t4.z; v[4 * m + 3] = t4.w;
    }
    float z[40];
#pragma unroll
    for (int c = 0; c < 40; ++c) {
        float a = b2s[c];
#pragma unroll
        for (int ff = 0; ff < NH; ++ff) a = fmaf(v[ff], w2s[ff * 40 + c], a);
        z[c] = a;
    }
    float mx = z[0];
#pragma unroll
    for (int c = 1; c < 40; ++c) mx = fmaxf(mx, z[c]);
    float sum = 0.0f;
#pragma unroll
    for (int c = 0; c < 40; ++c) sum += expf(z[c] - mx);
    float ls = mx + logf(sum);
    float4* op = (float4*)(out + (size_t)i * 40);
#pragma unroll
    for (int m = 0; m < 10; ++m) {
        float4 o;
        o.x = z[4 * m] - ls; o.y = z[4 * m + 1] - ls;
        o.z = z[4 * m + 2] - ls; o.w = z[4 * m + 3] - ls;
        op[m] = o;
    }
}

extern "C" void kernel_launch(void* const* d_in, const int* in_sizes, int n_in,
                              void* d_out, int out_size, void* d_ws, size_t ws_size,
                              hipStream_t stream) {
    const float* x  = (const float*)d_in[0];
    const int*   ei = (const int*)d_in[1];
    const float* ew = (const float*)d_in[2];
    const float* w1 = (const float*)d_in[3];
    const float* b1 = (const float*)d_in[4];
    const float* w2 = (const float*)d_in[5];
    const float* b2 = (const float*)d_in[6];
    float* out = (float*)d_out;

    int n = in_sizes[0] / NF;      // 100000 (= NRANGE*RS)
    int E = in_sizes[2];           // 3200000
    const int* src = ei;
    const int* dst = ei + E;

    float*    ws        = (float*)d_ws;
    float*    dinv      = ws;                       // n
    int*      bsum      = (int*)(ws + 200000);      // 1024
    int*      rowptr    = (int*)(ws + 201024);      // n+1
    int*      bsum2     = (int*)(ws + 301056);      // 1024
    int*      bktcnt    = (int*)(ws + 302080);      // 100032, scanned in place
    int*      partials  = (int*)(ws + 402112);      // 3.2M
    float*    wpartials = ws + 3602112;             // 3.2M
    unsigned* csr       = (unsigned*)(ws + 6802112);// E
    int2*     bin       = (int2*)(ws + 10002112);   // 2E, dead after fill3
    float*    h         = ws + 10002112;            // overlays bin
    float*    o1        = ws + 11602112;            // overlays bin

    int nblk  = (E + EB - 1) / EB;              // 3125 bin blocks
    int ncnt  = NRANGE * nblk;                  // 100000 counts
    int nb_c  = (ncnt + 255) / 256;             // 391
    int nb_n  = (n + 255) / 256;                // 391
    int nb_nf = (n * NH + 255) / 256;           // 6250
    int nb_g  = (n + GROWS - 1) / GROWS;        // 391 gemm blocks

    // 1) bin counts + bases (scan in place; block offsets applied inline)
    k_bincount<<<nblk, 256, 0, stream>>>(dst, bktcnt, E, nblk);
    k_scan_block<<<nb_c, 256, 0, stream>>>(bktcnt, bktcnt, bsum2, ncnt);
    k_scan_tops<<<1, 512, 0, stream>>>(bsum2, bktcnt, nb_c, ncnt);
    // 2) bin edges (each edge written once, single int2 scatter)
    k_binfill<<<nblk, 256, 0, stream>>>(src, dst, ew, bktcnt, bsum2, bin, E, nblk);
    // 3) hist (+weight sums) -> dinv+rowptr -> exact 4B CSR with baked nrm
    k_hist2<<<NRANGE * NS2, 256, 0, stream>>>(bin, bktcnt, bsum2, partials,
                                              wpartials, E, nblk);
    k_sumscan<<<nb_n, 256, 0, stream>>>(partials, wpartials, rowptr, bsum, dinv, n);
    k_scan_tops<<<1, 512, 0, stream>>>(bsum, rowptr, nb_n, n);
    k_scan_add<<<nb_n, 256, 0, stream>>>(rowptr, bsum, n);
    k_slicecur<<<nb_n, 256, 0, stream>>>(partials, rowptr, n);
    k_fill3<<<NRANGE * NS2, 256, 0, stream>>>(bin, bktcnt, bsum2, partials,
                                              dinv, csr, E, nblk);
    // 4) GCN pipeline
    k_gemm1<<<nb_g, 256, 0, stream>>>(x, w1, h, n);
    k_gather_relu<<<nb_nf, 256, 0, stream>>>(h, dinv, rowptr, csr, b1, o1, n);
    k_gather<<<nb_nf, 256, 0, stream>>>(o1, dinv, rowptr, csr, h, n);
    k_out<<<nb_n, 256, 0, stream>>>(h, w2, b2, out, n);
}

// Round 18
// 289.383 us; speedup vs baseline: 1.3320x; 1.3036x over previous
//
#include <hip/hip_runtime.h>

// GCN 2-layer. Round-17 plateau (373-385us, kernels <115us floor). Traffic
// math: gathers dominate -- E random 64B line fetches from 6.4MB h (205MB
// L2/L3) per pass. This round: h/o1 stored bf16 (fp32 accum, RNE pack) =>
// 32B lines, halved gather+stream traffic; gathers use 8 lanes/node with
// packed bf16x2 4B loads => half the wave-iterations. Build unchanged.

#define NF 512
#define NH 16
#define NRANGE 32
#define NS2 32
#define RS 3125           // nodes per range = 100000/32
#define EB 1024           // edges per bin block
#define GROWS 256         // gemm rows per block
#define GK 16             // gemm k-chunk (double-buffered)

__device__ __forceinline__ unsigned short f2bf(float f) {
    unsigned u = __float_as_uint(f);
    return (unsigned short)((u + 0x7fff + ((u >> 16) & 1)) >> 16);   // RNE
}
__device__ __forceinline__ float bf2f(unsigned b) {
    return __uint_as_float(b << 16);
}

// ---- ws layout (4B units) ----
// dinv @0 (100000) | bsum @200000 (1024) | rowptr @201024 (100001)
// bsum2 @301056 (1024) | bktcnt @302080 (100032)
// partials @402112 (3.2M int) | wpartials @3602112 (3.2M float)
// csr uint @6802112 (E) | bin int2 @10002112 (2E, dead after fill3)
// h bf16 @10002112 overlays bin (n*16 ushort = 800k f32-slots)
// o1 bf16 @10802112 overlays bin

__global__ __launch_bounds__(256) void k_bincount(const int* __restrict__ dst,
                                                  int* __restrict__ bktcnt,
                                                  int E, int nblk) {
    __shared__ int cnt[NRANGE];
    if (threadIdx.x < NRANGE) cnt[threadIdx.x] = 0;
    __syncthreads();
    int b0 = blockIdx.x * EB;
#pragma unroll
    for (int j = 0; j < 4; ++j) {
        int e = b0 + j * 256 + threadIdx.x;
        if (e < E) atomicAdd(&cnt[dst[e] / RS], 1);
    }
    __syncthreads();
    if (threadIdx.x < NRANGE)
        bktcnt[threadIdx.x * nblk + blockIdx.x] = cnt[threadIdx.x];
}

// exclusive scan (verified rounds 6-17); safe with out==in
__global__ __launch_bounds__(256) void k_scan_block(const int* __restrict__ in,
                                                    int* __restrict__ outp,
                                                    int* __restrict__ bsum, int n) {
    __shared__ int sh[256];
    int t = threadIdx.x, g = blockIdx.x * 256 + t;
    int v = (g < n) ? in[g] : 0;
    sh[t] = v; __syncthreads();
    for (int off = 1; off < 256; off <<= 1) {
        int a = (t >= off) ? sh[t - off] : 0;
        __syncthreads();
        sh[t] += a;
        __syncthreads();
    }
    if (g < n) outp[g] = sh[t] - v;
    if (t == 255) bsum[blockIdx.x] = sh[255];
}

// fused: per-node degree+weight reduction, dinv write, block scan of counts
__global__ __launch_bounds__(256) void k_sumscan(const int* __restrict__ partials,
                                                 const float* __restrict__ wpartials,
                                                 int* __restrict__ rowptr,
                                                 int* __restrict__ bsum,
                                                 float* __restrict__ dinv, int n) {
    __shared__ int sh[256];
    int t = threadIdx.x, g = blockIdx.x * 256 + t;
    int v = 0;
    if (g < n) {
        int r = g / RS, b = g - r * RS;
        size_t o = (size_t)(r * NS2) * RS + b;
        const int* p = partials + o;
        const float* wp = wpartials + o;
        float w = 1.0f;
#pragma unroll
        for (int s = 0; s < NS2; ++s) { v += p[s * RS]; w += wp[s * RS]; }
        dinv[g] = rsqrtf(w);
    }
    sh[t] = v; __syncthreads();
    for (int off = 1; off < 256; off <<= 1) {
        int a = (t >= off) ? sh[t - off] : 0;
        __syncthreads();
        sh[t] += a;
        __syncthreads();
    }
    if (g < n) rowptr[g] = sh[t] - v;
    if (t == 255) bsum[blockIdx.x] = sh[255];
}

__global__ __launch_bounds__(512) void k_scan_tops(int* __restrict__ bsum,
                                                   int* __restrict__ outp,
                                                   int nb, int n) {
    __shared__ int sh[512];
    int t = threadIdx.x;
    int v = (t < nb) ? bsum[t] : 0;
    sh[t] = v; __syncthreads();
    for (int off = 1; off < 512; off <<= 1) {
        int a = (t >= off) ? sh[t - off] : 0;
        __syncthreads();
        sh[t] += a;
        __syncthreads();
    }
    if (t < nb) bsum[t] = sh[t] - v;
    if (t == 511) outp[n] = sh[511];
}

__global__ __launch_bounds__(256) void k_scan_add(int* __restrict__ outp,
                                                  const int* __restrict__ bsum, int n) {
    int i = blockIdx.x * 256 + threadIdx.x;
    if (i < n) outp[i] += bsum[i >> 8];
}

// write each edge once into its bucket; bsum2 offset applied inline
__global__ __launch_bounds__(256) void k_binfill(const int* __restrict__ src,
                                                 const int* __restrict__ dst,
                                                 const float* __restrict__ ew,
                                                 const int* __restrict__ bktcnt,
                                                 const int* __restrict__ bsum2,
                                                 int2* __restrict__ bin,
                                                 int E, int nblk) {
    __shared__ int base[NRANGE];
    if (threadIdx.x < NRANGE) {
        int idx = threadIdx.x * nblk + blockIdx.x;
        base[threadIdx.x] = bktcnt[idx] + bsum2[idx >> 8];
    }
    __syncthreads();
    int b0 = blockIdx.x * EB;
#pragma unroll
    for (int j = 0; j < 4; ++j) {
        int e = b0 + j * 256 + threadIdx.x;
        if (e < E) {
            int d = dst[e];
            int r = d / RS;
            int pos = atomicAdd(&base[r], 1);          // LDS only
            bin[pos] = make_int2((src[e] << 12) | (d - r * RS),
                                 __float_as_int(ew[e]));
        }
    }
}

__device__ __forceinline__ int bkt_start(const int* bktcnt, const int* bsum2,
                                         int r, int nblk, int E) {
    if (r >= NRANGE) return E;
    int idx = r * nblk;
    return bktcnt[idx] + bsum2[idx >> 8];
}

// per-(range, slice) LDS histogram of counts AND edge-weight sums
__global__ __launch_bounds__(256) void k_hist2(const int2* __restrict__ bin,
                                               const int* __restrict__ bktcnt,
                                               const int* __restrict__ bsum2,
                                               int* __restrict__ partials,
                                               float* __restrict__ wpartials,
                                               int E, int nblk) {
    __shared__ int hist[RS];
    __shared__ float whist[RS];
    int r = blockIdx.x >> 5, s = blockIdx.x & (NS2 - 1);
    for (int t = threadIdx.x; t < RS; t += 256) { hist[t] = 0; whist[t] = 0.f; }
    __syncthreads();
    int b0 = bkt_start(bktcnt, bsum2, r, nblk, E);
    int b1 = bkt_start(bktcnt, bsum2, r + 1, nblk, E);
    int len = b1 - b0, ss = (len + NS2 - 1) / NS2;
    int cs = b0 + s * ss, ce = min(cs + ss, b1);
    for (int j = cs + threadIdx.x; j < ce; j += 256) {
        int2 p2 = bin[j];
        int dl = p2.x & 4095;
        atomicAdd(&hist[dl], 1);
        atomicAdd(&whist[dl], __int_as_float(p2.y));
    }
    __syncthreads();
    size_t o = (size_t)(r * NS2 + s) * RS;
    int* pp = partials + o;
    float* wpp = wpartials + o;
    for (int t = threadIdx.x; t < RS; t += 256) { pp[t] = hist[t]; wpp[t] = whist[t]; }
}

// per-slice counts -> exact slot starts
__global__ __launch_bounds__(256) void k_slicecur(int* __restrict__ partials,
                                                  const int* __restrict__ rowptr, int n) {
    int d = blockIdx.x * 256 + threadIdx.x;
    if (d >= n) return;
    int r = d / RS, b = d - r * RS;
    int* p = partials + (size_t)(r * NS2) * RS + b;
    int run = rowptr[d];
#pragma unroll
    for (int s = 0; s < NS2; ++s) {
        int c = p[s * RS];
        p[s * RS] = run;
        run += c;
    }
}

// place edges: csr = (src<<15) | fixed15(dinv[s]*ew*dinv[d])
__global__ __launch_bounds__(256) void k_fill3(const int2* __restrict__ bin,
                                               const int* __restrict__ bktcnt,
                                               const int* __restrict__ bsum2,
                                               const int* __restrict__ partials,
                                               const float* __restrict__ dinv,
                                               unsigned* __restrict__ csr,
                                               int E, int nblk) {
    __shared__ int cur[RS];
    __shared__ float dv[RS];
    int r = blockIdx.x >> 5, s = blockIdx.x & (NS2 - 1);
    const int* cp = partials + (size_t)(r * NS2 + s) * RS;
    for (int t = threadIdx.x; t < RS; t += 256) {
        cur[t] = cp[t];
        dv[t] = dinv[r * RS + t];
    }
    __syncthreads();
    int b0 = bkt_start(bktcnt, bsum2, r, nblk, E);
    int b1 = bkt_start(bktcnt, bsum2, r + 1, nblk, E);
    int len = b1 - b0, ss = (len + NS2 - 1) / NS2;
    int cs = b0 + s * ss, ce = min(cs + ss, b1);
    for (int j = cs + threadIdx.x; j < ce; j += 256) {
        int2 p2 = bin[j];
        int dl = p2.x & 4095;
        int sn = p2.x >> 12;
        float nrm = dinv[sn] * __int_as_float(p2.y) * dv[dl];
        unsigned w15 = (unsigned)(nrm * 32767.0f + 0.5f);
        int pos = atomicAdd(&cur[dl], 1);             // LDS only
        csr[pos] = ((unsigned)sn << 15) | w15;
    }
}

// h = x @ W1 (373us-measured structure) with bf16 output (ushort4 packs)
__global__ __launch_bounds__(256) void k_gemm1(const float* __restrict__ x,
                                               const float* __restrict__ w1,
                                               unsigned short* __restrict__ h, int n) {
    __shared__ float wt[NF * NH];          // 32KB, read-only after init
    __shared__ float xs[2][GROWS * GK];    // 2 x 16KB
    for (int t = threadIdx.x; t < NF * NH; t += 256) {
        int k = t >> 4, f = t & 15;
        wt[(k >> 2) * 64 + (f << 2) + (k & 3)] = w1[t];
    }
    int rq = threadIdx.x >> 2;             // 0..63 (row quad)
    int fq = threadIdx.x & 3;              // 0..3  (col quad)
    int base = blockIdx.x * GROWS;
    float4 stage[4];
#define LOAD_CHUNK(kc)                                                        \
    _Pragma("unroll")                                                         \
    for (int li = 0; li < 4; ++li) {                                          \
        int idx = li * 256 + threadIdx.x;                                     \
        int row = idx >> 2, c4 = idx & 3;                                     \
        int rg = base + row; if (rg > n - 1) rg = n - 1;                      \
        stage[li] = *(const float4*)(x + (size_t)rg * NF + (kc) * GK + c4 * 4);\
    }
#define WRITE_CHUNK(b)                                                        \
    _Pragma("unroll")                                                         \
    for (int li = 0; li < 4; ++li) {                                          \
        int idx = li * 256 + threadIdx.x;                                     \
        int row = idx >> 2, c4 = idx & 3;                                     \
        int slot = (c4 + (row >> 2)) & 3;                                     \
        float* p = &xs[b][row * GK + slot * 4];                               \
        p[0] = stage[li].x; p[1] = stage[li].y;                               \
        p[2] = stage[li].z; p[3] = stage[li].w;                               \
    }
    float acc[4][4] = {{0.f}};
    LOAD_CHUNK(0)
    WRITE_CHUNK(0)
    __syncthreads();                       // also covers wt
    for (int kc = 0; kc < NF / GK; ++kc) {
        if (kc + 1 < NF / GK) { LOAD_CHUNK(kc + 1) }   // in flight over compute
        int b = kc & 1;
#pragma unroll
        for (int k4c = 0; k4c < GK / 4; ++k4c) {
            int k4 = kc * (GK / 4) + k4c;
            float4 wf[4];
#pragma unroll
            for (int c = 0; c < 4; ++c)
                wf[c] = *(const float4*)&wt[k4 * 64 + (fq * 4 + c) * 4];
#pragma unroll
            for (int i = 0; i < 4; ++i) {
                int row = rq * 4 + i;
                int slot = (k4c + rq) & 3;
                float4 xv = *(const float4*)&xs[b][row * GK + slot * 4];
#pragma unroll
                for (int c = 0; c < 4; ++c) {
                    acc[i][c] = fmaf(xv.x, wf[c].x, acc[i][c]);
                    acc[i][c] = fmaf(xv.y, wf[c].y, acc[i][c]);
                    acc[i][c] = fmaf(xv.z, wf[c].z, acc[i][c]);
                    acc[i][c] = fmaf(xv.w, wf[c].w, acc[i][c]);
                }
            }
        }
        if (kc + 1 < NF / GK) {
            __syncthreads();               // all lanes done with buf b^1 reads
            WRITE_CHUNK((kc + 1) & 1)      // drains vmcnt here, behind compute
            __syncthreads();               // writes visible for next chunk
        }
    }
#pragma unroll
    for (int i = 0; i < 4; ++i) {
        int r = base + rq * 4 + i;
        if (r < n) {
            ushort4 o;
            o.x = f2bf(acc[i][0]); o.y = f2bf(acc[i][1]);
            o.z = f2bf(acc[i][2]); o.w = f2bf(acc[i][3]);
            *(ushort4*)(h + (size_t)r * NH + fq * 4) = o;   // 8B aligned
        }
    }
#undef LOAD_CHUNK
#undef WRITE_CHUNK
}

// gathers: 8 lanes/node, 2 features/lane, packed bf16x2 4B loads.
// out[d][2l,2l+1] = act(self*di^2 + sum nrm*in[src][2l,2l+1])
template <bool RELU>
__global__ __launch_bounds__(256) void k_gatherT(const unsigned short* __restrict__ in,
                                                 const float* __restrict__ dinv,
                                                 const int* __restrict__ rowptr,
                                                 const unsigned* __restrict__ csr,
                                                 const float* __restrict__ b1,
                                                 unsigned short* __restrict__ out, int n) {
    int tid = blockIdx.x * 256 + threadIdx.x;
    int d = tid >> 3, l = tid & 7;
    if (d >= n) return;
    float di = dinv[d];
    unsigned self = *(const unsigned*)(in + (size_t)d * NH + 2 * l);
    float a0 = bf2f(self & 0xffffu) * di * di;
    float a1 = bf2f(self >> 16) * di * di;
    int e0 = rowptr[d], e1 = rowptr[d + 1];
    for (int j = e0; j < e1; ++j) {
        unsigned e = csr[j];                          // 4B broadcast (8-lane)
        float nrm = (float)(e & 32767u) * (1.0f / 32767.0f);
        unsigned pr = *(const unsigned*)(in + (size_t)(e >> 15) * NH + 2 * l);
        a0 = fmaf(bf2f(pr & 0xffffu), nrm, a0);
        a1 = fmaf(bf2f(pr >> 16), nrm, a1);
    }
    if (RELU) {
        a0 = fmaxf(a0 + b1[2 * l], 0.0f);
        a1 = fmaxf(a1 + b1[2 * l + 1], 0.0f);
    }
    unsigned pk = (unsigned)f2bf(a0) | ((unsigned)f2bf(a1) << 16);
    *(unsigned*)(out + (size_t)d * NH + 2 * l) = pk;
}

__global__ __launch_bounds__(256) void k_out(const unsigned short* __restrict__ agg,
                                             const float* __restrict__ w2,
                                             const float* __restrict__ b2,
                                             float* __restrict__ out, int n) {
    __shared__ float w2s[NH * 40];
    __shared__ float b2s[40];
    for (int t = threadIdx.x; t < NH * 40; t += 256) w2s[t] = w2[t];
    if (threadIdx.x < 40) b2s[threadIdx.x] = b2[threadIdx.x];
    __syncthreads();
    int i = blockIdx.x * 256 + threadIdx.x;
    if (i >= n) return;
    float v[NH];
    const uint4* ap = (const uint4*)(agg + (size_t)i * NH);   // 32B row
#pragma unroll
    for (int m = 0; m < 2; ++m) {
        uint4 q = ap[m];
        v[8 * m + 0] = bf2f(q.x & 0xffffu); v[8 * m + 1] = bf2f(q.x >> 16);
        v[8 * m + 2] = bf2f(q.y & 0xffffu); v[8 * m + 3] = bf2f(q.y >> 16);
        v[8 * m + 4] = bf2f(q.z & 0xffffu); v[8 * m + 5] = bf2f(q.z >> 16);
        v[8 * m + 6] = bf2f(q.w & 0xffffu); v[8 * m + 7] = bf2f(q.w >> 16);
    }
    float z[40];
#pragma unroll
    for (int c = 0; c < 40; ++c) {
        float a = b2s[c];
#pragma unroll
        for (int ff = 0; ff < NH; ++ff) a = fmaf(v[ff], w2s[ff * 40 + c], a);
        z[c] = a;
    }
    float mx = z[0];
#pragma unroll
    for (int c = 1; c < 40; ++c) mx = fmaxf(mx, z[c]);
    float sum = 0.0f;
#pragma unroll
    for (int c = 0; c < 40; ++c) sum += expf(z[c] - mx);
    float ls = mx + logf(sum);
    float4* op = (float4*)(out + (size_t)i * 40);
#pragma unroll
    for (int m = 0; m < 10; ++m) {
        float4 o;
        o.x = z[4 * m] - ls; o.y = z[4 * m + 1] - ls;
        o.z = z[4 * m + 2] - ls; o.w = z[4 * m + 3] - ls;
        op[m] = o;
    }
}

extern "C" void kernel_launch(void* const* d_in, const int* in_sizes, int n_in,
                              void* d_out, int out_size, void* d_ws, size_t ws_size,
                              hipStream_t stream) {
    const float* x  = (const float*)d_in[0];
    const int*   ei = (const int*)d_in[1];
    const float* ew = (const float*)d_in[2];
    const float* w1 = (const float*)d_in[3];
    const float* b1 = (const float*)d_in[4];
    const float* w2 = (const float*)d_in[5];
    const float* b2 = (const float*)d_in[6];
    float* out = (float*)d_out;

    int n = in_sizes[0] / NF;      // 100000 (= NRANGE*RS)
    int E = in_sizes[2];           // 3200000
    const int* src = ei;
    const int* dst = ei + E;

    float*          ws        = (float*)d_ws;
    float*          dinv      = ws;                        // n
    int*            bsum      = (int*)(ws + 200000);       // 1024
    int*            rowptr    = (int*)(ws + 201024);       // n+1
    int*            bsum2     = (int*)(ws + 301056);       // 1024
    int*            bktcnt    = (int*)(ws + 302080);       // 100032
    int*            partials  = (int*)(ws + 402112);       // 3.2M
    float*          wpartials = ws + 3602112;              // 3.2M
    unsigned*       csr       = (unsigned*)(ws + 6802112); // E
    int2*           bin       = (int2*)(ws + 10002112);    // 2E, dead after fill3
    unsigned short* h         = (unsigned short*)(ws + 10002112);  // overlays bin
    unsigned short* o1        = (unsigned short*)(ws + 10802112);  // overlays bin

    int nblk  = (E + EB - 1) / EB;              // 3125 bin blocks
    int ncnt  = NRANGE * nblk;                  // 100000 counts
    int nb_c  = (ncnt + 255) / 256;             // 391
    int nb_n  = (n + 255) / 256;                // 391
    int nb_g8 = (n * 8 + 255) / 256;            // 3125 gather blocks
    int nb_g  = (n + GROWS - 1) / GROWS;        // 391 gemm blocks

    // 1) bin counts + bases (scan in place; block offsets applied inline)
    k_bincount<<<nblk, 256, 0, stream>>>(dst, bktcnt, E, nblk);
    k_scan_block<<<nb_c, 256, 0, stream>>>(bktcnt, bktcnt, bsum2, ncnt);
    k_scan_tops<<<1, 512, 0, stream>>>(bsum2, bktcnt, nb_c, ncnt);
    // 2) bin edges (each edge written once, single int2 scatter)
    k_binfill<<<nblk, 256, 0, stream>>>(src, dst, ew, bktcnt, bsum2, bin, E, nblk);
    // 3) hist (+weight sums) -> dinv+rowptr -> exact 4B CSR with baked nrm
    k_hist2<<<NRANGE * NS2, 256, 0, stream>>>(bin, bktcnt, bsum2, partials,
                                              wpartials, E, nblk);
    k_sumscan<<<nb_n, 256, 0, stream>>>(partials, wpartials, rowptr, bsum, dinv, n);
    k_scan_tops<<<1, 512, 0, stream>>>(bsum, rowptr, nb_n, n);
    k_scan_add<<<nb_n, 256, 0, stream>>>(rowptr, bsum, n);
    k_slicecur<<<nb_n, 256, 0, stream>>>(partials, rowptr, n);
    k_fill3<<<NRANGE * NS2, 256, 0, stream>>>(bin, bktcnt, bsum2, partials,
                                              dinv, csr, E, nblk);
    // 4) GCN pipeline (bf16 h/o1)
    k_gemm1<<<nb_g, 256, 0, stream>>>(x, w1, h, n);
    k_gatherT<true><<<nb_g8, 256, 0, stream>>>(h, dinv, rowptr, csr, b1, o1, n);
    k_gatherT<false><<<nb_g8, 256, 0, stream>>>(o1, dinv, rowptr, csr, b1, h, n);
    k_out<<<nb_n, 256, 0, stream>>>(h, w2, b2, out, n);
}

// Round 19
// 279.166 us; speedup vs baseline: 1.3808x; 1.0366x over previous
//
#include <hip/hip_runtime.h>

// GCN 2-layer. Round-18: 289us (-88, bf16 gathers). This round:
// (1) gemm1 W1 stored bf16 in LDS (16KB, unpack=1 inst/float): 48KB LDS
//     -> 3 blocks/CU (was 2), b64 wf reads. (2) build: packed single
//     histogram (count<<25 | round(ew*1024)) -> one LDS atomic + half the
//     partials traffic. dinv quant err ~1e-3 (vs bf16 storage 4e-3).

#define NF 512
#define NH 16
#define NRANGE 32
#define NS2 32
#define RS 3125           // nodes per range = 100000/32
#define EB 1024           // edges per bin block
#define GROWS 256         // gemm rows per block
#define GK 16             // gemm k-chunk (double-buffered)

__device__ __forceinline__ unsigned short f2bf(float f) {
    unsigned u = __float_as_uint(f);
    return (unsigned short)((u + 0x7fff + ((u >> 16) & 1)) >> 16);   // RNE
}
__device__ __forceinline__ float bf2f(unsigned b) {
    return __uint_as_float(b << 16);
}

// ---- ws layout (4B units) ----
// dinv @0 (100000) | bsum @200000 (1024) | rowptr @201024 (100001)
// bsum2 @301056 (1024) | bktcnt @302080 (100032)
// partials @402112 (3.2M uint, packed count|wsum)
// csr uint @6802112 (E) | bin int2 @10002112 (2E, dead after fill3)
// h bf16 @10002112 overlays bin | o1 bf16 @10802112 overlays bin

__global__ __launch_bounds__(256) void k_bincount(const int* __restrict__ dst,
                                                  int* __restrict__ bktcnt,
                                                  int E, int nblk) {
    __shared__ int cnt[NRANGE];
    if (threadIdx.x < NRANGE) cnt[threadIdx.x] = 0;
    __syncthreads();
    int b0 = blockIdx.x * EB;
#pragma unroll
    for (int j = 0; j < 4; ++j) {
        int e = b0 + j * 256 + threadIdx.x;
        if (e < E) atomicAdd(&cnt[dst[e] / RS], 1);
    }
    __syncthreads();
    if (threadIdx.x < NRANGE)
        bktcnt[threadIdx.x * nblk + blockIdx.x] = cnt[threadIdx.x];
}

// exclusive scan (verified rounds 6-18); safe with out==in
__global__ __launch_bounds__(256) void k_scan_block(const int* __restrict__ in,
                                                    int* __restrict__ outp,
                                                    int* __restrict__ bsum, int n) {
    __shared__ int sh[256];
    int t = threadIdx.x, g = blockIdx.x * 256 + t;
    int v = (g < n) ? in[g] : 0;
    sh[t] = v; __syncthreads();
    for (int off = 1; off < 256; off <<= 1) {
        int a = (t >= off) ? sh[t - off] : 0;
        __syncthreads();
        sh[t] += a;
        __syncthreads();
    }
    if (g < n) outp[g] = sh[t] - v;
    if (t == 255) bsum[blockIdx.x] = sh[255];
}

// fused: per-node degree+weight reduction (packed), dinv write, block scan
__global__ __launch_bounds__(256) void k_sumscan(const unsigned* __restrict__ partials,
                                                 int* __restrict__ rowptr,
                                                 int* __restrict__ bsum,
                                                 float* __restrict__ dinv, int n) {
    __shared__ int sh[256];
    int t = threadIdx.x, g = blockIdx.x * 256 + t;
    int v = 0;
    if (g < n) {
        int r = g / RS, b = g - r * RS;
        const unsigned* p = partials + (size_t)(r * NS2) * RS + b;
        unsigned wq = 0;
#pragma unroll
        for (int s = 0; s < NS2; ++s) {
            unsigned pk = p[s * RS];
            v += (int)(pk >> 25);
            wq += pk & 0x1ffffffu;
        }
        dinv[g] = rsqrtf(1.0f + (float)wq * (1.0f / 1024.0f));
    }
    sh[t] = v; __syncthreads();
    for (int off = 1; off < 256; off <<= 1) {
        int a = (t >= off) ? sh[t - off] : 0;
        __syncthreads();
        sh[t] += a;
        __syncthreads();
    }
    if (g < n) rowptr[g] = sh[t] - v;
    if (t == 255) bsum[blockIdx.x] = sh[255];
}

__global__ __launch_bounds__(512) void k_scan_tops(int* __restrict__ bsum,
                                                   int* __restrict__ outp,
                                                   int nb, int n) {
    __shared__ int sh[512];
    int t = threadIdx.x;
    int v = (t < nb) ? bsum[t] : 0;
    sh[t] = v; __syncthreads();
    for (int off = 1; off < 512; off <<= 1) {
        int a = (t >= off) ? sh[t - off] : 0;
        __syncthreads();
        sh[t] += a;
        __syncthreads();
    }
    if (t < nb) bsum[t] = sh[t] - v;
    if (t == 511) outp[n] = sh[511];
}

__global__ __launch_bounds__(256) void k_scan_add(int* __restrict__ outp,
                                                  const int* __restrict__ bsum, int n) {
    int i = blockIdx.x * 256 + threadIdx.x;
    if (i < n) outp[i] += bsum[i >> 8];
}

// write each edge once into its bucket; bsum2 offset applied inline
__global__ __launch_bounds__(256) void k_binfill(const int* __restrict__ src,
                                                 const int* __restrict__ dst,
                                                 const float* __restrict__ ew,
                                                 const int* __restrict__ bktcnt,
                                                 const int* __restrict__ bsum2,
                                                 int2* __restrict__ bin,
                                                 int E, int nblk) {
    __shared__ int base[NRANGE];
    if (threadIdx.x < NRANGE) {
        int idx = threadIdx.x * nblk + blockIdx.x;
        base[threadIdx.x] = bktcnt[idx] + bsum2[idx >> 8];
    }
    __syncthreads();
    int b0 = blockIdx.x * EB;
#pragma unroll
    for (int j = 0; j < 4; ++j) {
        int e = b0 + j * 256 + threadIdx.x;
        if (e < E) {
            int d = dst[e];
            int r = d / RS;
            int pos = atomicAdd(&base[r], 1);          // LDS only
            bin[pos] = make_int2((src[e] << 12) | (d - r * RS),
                                 __float_as_int(ew[e]));
        }
    }
}

__device__ __forceinline__ int bkt_start(const int* bktcnt, const int* bsum2,
                                         int r, int nblk, int E) {
    if (r >= NRANGE) return E;
    int idx = r * nblk;
    return bktcnt[idx] + bsum2[idx >> 8];
}

// per-(range, slice) packed LDS histogram: (count<<25) | sum(round(ew*1024))
__global__ __launch_bounds__(256) void k_hist2(const int2* __restrict__ bin,
                                               const int* __restrict__ bktcnt,
                                               const int* __restrict__ bsum2,
                                               unsigned* __restrict__ partials,
                                               int E, int nblk) {
    __shared__ unsigned hist[RS];
    int r = blockIdx.x >> 5, s = blockIdx.x & (NS2 - 1);
    for (int t = threadIdx.x; t < RS; t += 256) hist[t] = 0;
    __syncthreads();
    int b0 = bkt_start(bktcnt, bsum2, r, nblk, E);
    int b1 = bkt_start(bktcnt, bsum2, r + 1, nblk, E);
    int len = b1 - b0, ss = (len + NS2 - 1) / NS2;
    int cs = b0 + s * ss, ce = min(cs + ss, b1);
    for (int j = cs + threadIdx.x; j < ce; j += 256) {
        int2 p2 = bin[j];
        unsigned wq = (unsigned)(__int_as_float(p2.y) * 1024.0f + 0.5f);
        atomicAdd(&hist[p2.x & 4095], (1u << 25) | wq);
    }
    __syncthreads();
    unsigned* pp = partials + (size_t)(r * NS2 + s) * RS;
    for (int t = threadIdx.x; t < RS; t += 256) pp[t] = hist[t];
}

// per-slice packed counts -> exact slot starts (overwrites packed)
__global__ __launch_bounds__(256) void k_slicecur(unsigned* __restrict__ partials,
                                                  const int* __restrict__ rowptr, int n) {
    int d = blockIdx.x * 256 + threadIdx.x;
    if (d >= n) return;
    int r = d / RS, b = d - r * RS;
    unsigned* p = partials + (size_t)(r * NS2) * RS + b;
    int run = rowptr[d];
#pragma unroll
    for (int s = 0; s < NS2; ++s) {
        int c = (int)(p[s * RS] >> 25);
        p[s * RS] = (unsigned)run;
        run += c;
    }
}

// place edges: csr = (src<<15) | fixed15(dinv[s]*ew*dinv[d])
__global__ __launch_bounds__(256) void k_fill3(const int2* __restrict__ bin,
                                               const int* __restrict__ bktcnt,
                                               const int* __restrict__ bsum2,
                                               const unsigned* __restrict__ partials,
                                               const float* __restrict__ dinv,
                                               unsigned* __restrict__ csr,
                                               int E, int nblk) {
    __shared__ int cur[RS];
    __shared__ float dv[RS];
    int r = blockIdx.x >> 5, s = blockIdx.x & (NS2 - 1);
    const unsigned* cp = partials + (size_t)(r * NS2 + s) * RS;
    for (int t = threadIdx.x; t < RS; t += 256) {
        cur[t] = (int)cp[t];
        dv[t] = dinv[r * RS + t];
    }
    __syncthreads();
    int b0 = bkt_start(bktcnt, bsum2, r, nblk, E);
    int b1 = bkt_start(bktcnt, bsum2, r + 1, nblk, E);
    int len = b1 - b0, ss = (len + NS2 - 1) / NS2;
    int cs = b0 + s * ss, ce = min(cs + ss, b1);
    for (int j = cs + threadIdx.x; j < ce; j += 256) {
        int2 p2 = bin[j];
        int dl = p2.x & 4095;
        int sn = p2.x >> 12;
        float nrm = dinv[sn] * __int_as_float(p2.y) * dv[dl];
        unsigned w15 = (unsigned)(nrm * 32767.0f + 0.5f);
        int pos = atomicAdd(&cur[dl], 1);             // LDS only
        csr[pos] = ((unsigned)sn << 15) | w15;
    }
}

// h = x @ W1: dbuf xs (fp32) + bf16 W1 in LDS (16KB) -> 48KB, 3 blocks/CU
__global__ __launch_bounds__(256) void k_gemm1(const float* __restrict__ x,
                                               const float* __restrict__ w1,
                                               unsigned short* __restrict__ h, int n) {
    __shared__ unsigned wtb[NF * NH / 2];  // 16KB: [k4][c16][kk/2] bf16 pairs
    __shared__ float xs[2][GROWS * GK];    // 2 x 16KB
    for (int idx = threadIdx.x; idx < NF * NH / 2; idx += 256) {
        int k4 = idx >> 5, rem = idx & 31;
        int f = rem >> 1, kk = (rem & 1) * 2;
        float v0 = w1[(k4 * 4 + kk) * NH + f];
        float v1 = w1[(k4 * 4 + kk + 1) * NH + f];
        wtb[idx] = (unsigned)f2bf(v0) | ((unsigned)f2bf(v1) << 16);
    }
    int rq = threadIdx.x >> 2;             // 0..63 (row quad)
    int fq = threadIdx.x & 3;              // 0..3  (col quad)
    int base = blockIdx.x * GROWS;
    float4 stage[4];
#define LOAD_CHUNK(kc)                                                        \
    _Pragma("unroll")                                                         \
    for (int li = 0; li < 4; ++li) {                                          \
        int idx = li * 256 + threadIdx.x;                                     \
        int row = idx >> 2, c4 = idx & 3;                                     \
        int rg = base + row; if (rg > n - 1) rg = n - 1;                      \
        stage[li] = *(const float4*)(x + (size_t)rg * NF + (kc) * GK + c4 * 4);\
    }
#define WRITE_CHUNK(b)                                                        \
    _Pragma("unroll")                                                         \
    for (int li = 0; li < 4; ++li) {                                          \
        int idx = li * 256 + threadIdx.x;                                     \
        int row = idx >> 2, c4 = idx & 3;                                     \
        int slot = (c4 + (row >> 2)) & 3;                                     \
        float* p = &xs[b][row * GK + slot * 4];                               \
        p[0] = stage[li].x; p[1] = stage[li].y;                               \
        p[2] = stage[li].z; p[3] = stage[li].w;                               \
    }
    float acc[4][4] = {{0.f}};
    LOAD_CHUNK(0)
    WRITE_CHUNK(0)
    __syncthreads();                       // also covers wtb
    for (int kc = 0; kc < NF / GK; ++kc) {
        if (kc + 1 < NF / GK) { LOAD_CHUNK(kc + 1) }   // in flight over compute
        int b = kc & 1;
#pragma unroll
        for (int k4c = 0; k4c < GK / 4; ++k4c) {
            int k4 = kc * (GK / 4) + k4c;
            float4 wf[4];
#pragma unroll
            for (int c = 0; c < 4; ++c) {
                uint2 u = *(const uint2*)&wtb[k4 * 32 + (fq * 4 + c) * 2];
                wf[c].x = __uint_as_float(u.x << 16);
                wf[c].y = __uint_as_float(u.x & 0xffff0000u);
                wf[c].z = __uint_as_float(u.y << 16);
                wf[c].w = __uint_as_float(u.y & 0xffff0000u);
            }
#pragma unroll
            for (int i = 0; i < 4; ++i) {
                int row = rq * 4 + i;
                int slot = (k4c + rq) & 3;
                float4 xv = *(const float4*)&xs[b][row * GK + slot * 4];
#pragma unroll
                for (int c = 0; c < 4; ++c) {
                    acc[i][c] = fmaf(xv.x, wf[c].x, acc[i][c]);
                    acc[i][c] = fmaf(xv.y, wf[c].y, acc[i][c]);
                    acc[i][c] = fmaf(xv.z, wf[c].z, acc[i][c]);
                    acc[i][c] = fmaf(xv.w, wf[c].w, acc[i][c]);
                }
            }
        }
        if (kc + 1 < NF / GK) {
            __syncthreads();               // all lanes done with buf b^1 reads
            WRITE_CHUNK((kc + 1) & 1)      // drains vmcnt here, behind compute
            __syncthreads();               // writes visible for next chunk
        }
    }
#pragma unroll
    for (int i = 0; i < 4; ++i) {
        int r = base + rq * 4 + i;
        if (r < n) {
            ushort4 o;
            o.x = f2bf(acc[i][0]); o.y = f2bf(acc[i][1]);
            o.z = f2bf(acc[i][2]); o.w = f2bf(acc[i][3]);
            *(ushort4*)(h + (size_t)r * NH + fq * 4) = o;   // 8B aligned
        }
    }
#undef LOAD_CHUNK
#undef WRITE_CHUNK
}

// gathers: 8 lanes/node, 2 features/lane, packed bf16x2 4B loads
template <bool RELU>
__global__ __launch_bounds__(256) void k_gatherT(const unsigned short* __restrict__ in,
                                                 const float* __restrict__ dinv,
                                                 const int* __restrict__ rowptr,
                                                 const unsigned* __restrict__ csr,
                                                 const float* __restrict__ b1,
                                                 unsigned short* __restrict__ out, int n) {
    int tid = blockIdx.x * 256 + threadIdx.x;
    int d = tid >> 3, l = tid & 7;
    if (d >= n) return;
    float di = dinv[d];
    unsigned self = *(const unsigned*)(in + (size_t)d * NH + 2 * l);
    float a0 = bf2f(self & 0xffffu) * di * di;
    float a1 = bf2f(self >> 16) * di * di;
    int e0 = rowptr[d], e1 = rowptr[d + 1];
    for (int j = e0; j < e1; ++j) {
        unsigned e = csr[j];                          // 4B broadcast (8-lane)
        float nrm = (float)(e & 32767u) * (1.0f / 32767.0f);
        unsigned pr = *(const unsigned*)(in + (size_t)(e >> 15) * NH + 2 * l);
        a0 = fmaf(bf2f(pr & 0xffffu), nrm, a0);
        a1 = fmaf(bf2f(pr >> 16), nrm, a1);
    }
    if (RELU) {
        a0 = fmaxf(a0 + b1[2 * l], 0.0f);
        a1 = fmaxf(a1 + b1[2 * l + 1], 0.0f);
    }
    unsigned pk = (unsigned)f2bf(a0) | ((unsigned)f2bf(a1) << 16);
    *(unsigned*)(out + (size_t)d * NH + 2 * l) = pk;
}

__global__ __launch_bounds__(256) void k_out(const unsigned short* __restrict__ agg,
                                             const float* __restrict__ w2,
                                             const float* __restrict__ b2,
                                             float* __restrict__ out, int n) {
    __shared__ float w2s[NH * 40];
    __shared__ float b2s[40];
    for (int t = threadIdx.x; t < NH * 40; t += 256) w2s[t] = w2[t];
    if (threadIdx.x < 40) b2s[threadIdx.x] = b2[threadIdx.x];
    __syncthreads();
    int i = blockIdx.x * 256 + threadIdx.x;
    if (i >= n) return;
    float v[NH];
    const uint4* ap = (const uint4*)(agg + (size_t)i * NH);   // 32B row
#pragma unroll
    for (int m = 0; m < 2; ++m) {
        uint4 q = ap[m];
        v[8 * m + 0] = bf2f(q.x & 0xffffu); v[8 * m + 1] = bf2f(q.x >> 16);
        v[8 * m + 2] = bf2f(q.y & 0xffffu); v[8 * m + 3] = bf2f(q.y >> 16);
        v[8 * m + 4] = bf2f(q.z & 0xffffu); v[8 * m + 5] = bf2f(q.z >> 16);
        v[8 * m + 6] = bf2f(q.w & 0xffffu); v[8 * m + 7] = bf2f(q.w >> 16);
    }
    float z[40];
#pragma unroll
    for (int c = 0; c < 40; ++c) {
        float a = b2s[c];
#pragma unroll
        for (int ff = 0; ff < NH; ++ff) a = fmaf(v[ff], w2s[ff * 40 + c], a);
        z[c] = a;
    }
    float mx = z[0];
#pragma unroll
    for (int c = 1; c < 40; ++c) mx = fmaxf(mx, z[c]);
    float sum = 0.0f;
#pragma unroll
    for (int c = 0; c < 40; ++c) sum += expf(z[c] - mx);
    float ls = mx + logf(sum);
    float4* op = (float4*)(out + (size_t)i * 40);
#pragma unroll
    for (int m = 0; m < 10; ++m) {
        float4 o;
        o.x = z[4 * m] - ls; o.y = z[4 * m + 1] - ls;
        o.z = z[4 * m + 2] - ls; o.w = z[4 * m + 3] - ls;
        op[m] = o;
    }
}

extern "C" void kernel_launch(void* const* d_in, const int* in_sizes, int n_in,
                              void* d_out, int out_size, void* d_ws, size_t ws_size,
                              hipStream_t stream) {
    const float* x  = (const float*)d_in[0];
    const int*   ei = (const int*)d_in[1];
    const float* ew = (const float*)d_in[2];
    const float* w1 = (const float*)d_in[3];
    const float* b1 = (const float*)d_in[4];
    const float* w2 = (const float*)d_in[5];
    const float* b2 = (const float*)d_in[6];
    float* out = (float*)d_out;

    int n = in_sizes[0] / NF;      // 100000 (= NRANGE*RS)
    int E = in_sizes[2];           // 3200000
    const int* src = ei;
    const int* dst = ei + E;

    float*          ws       = (float*)d_ws;
    float*          dinv     = ws;                        // n
    int*            bsum     = (int*)(ws + 200000);       // 1024
    int*            rowptr   = (int*)(ws + 201024);       // n+1
    int*            bsum2    = (int*)(ws + 301056);       // 1024
    int*            bktcnt   = (int*)(ws + 302080);       // 100032
    unsigned*       partials = (unsigned*)(ws + 402112);  // 3.2M packed
    unsigned*       csr      = (unsigned*)(ws + 6802112); // E
    int2*           bin      = (int2*)(ws + 10002112);    // 2E, dead after fill3
    unsigned short* h        = (unsigned short*)(ws + 10002112);  // overlays bin
    unsigned short* o1       = (unsigned short*)(ws + 10802112);  // overlays bin

    int nblk  = (E + EB - 1) / EB;              // 3125 bin blocks
    int ncnt  = NRANGE * nblk;                  // 100000 counts
    int nb_c  = (ncnt + 255) / 256;             // 391
    int nb_n  = (n + 255) / 256;                // 391
    int nb_g8 = (n * 8 + 255) / 256;            // 3125 gather blocks
    int nb_g  = (n + GROWS - 1) / GROWS;        // 391 gemm blocks

    // 1) bin counts + bases (scan in place; block offsets applied inline)
    k_bincount<<<nblk, 256, 0, stream>>>(dst, bktcnt, E, nblk);
    k_scan_block<<<nb_c, 256, 0, stream>>>(bktcnt, bktcnt, bsum2, ncnt);
    k_scan_tops<<<1, 512, 0, stream>>>(bsum2, bktcnt, nb_c, ncnt);
    // 2) bin edges (each edge written once, single int2 scatter)
    k_binfill<<<nblk, 256, 0, stream>>>(src, dst, ew, bktcnt, bsum2, bin, E, nblk);
    // 3) packed hist -> dinv+rowptr -> exact 4B CSR with baked nrm
    k_hist2<<<NRANGE * NS2, 256, 0, stream>>>(bin, bktcnt, bsum2, partials, E, nblk);
    k_sumscan<<<nb_n, 256, 0, stream>>>(partials, rowptr, bsum, dinv, n);
    k_scan_tops<<<1, 512, 0, stream>>>(bsum, rowptr, nb_n, n);
    k_scan_add<<<nb_n, 256, 0, stream>>>(rowptr, bsum, n);
    k_slicecur<<<nb_n, 256, 0, stream>>>(partials, rowptr, n);
    k_fill3<<<NRANGE * NS2, 256, 0, stream>>>(bin, bktcnt, bsum2, partials,
                                              dinv, csr, E, nblk);
    // 4) GCN pipeline (bf16 h/o1)
    k_gemm1<<<nb_g, 256, 0, stream>>>(x, w1, h, n);
    k_gatherT<true><<<nb_g8, 256, 0, stream>>>(h, dinv, rowptr, csr, b1, o1, n);
    k_gatherT<false><<<nb_g8, 256, 0, stream>>>(o1, dinv, rowptr, csr, b1, h, n);
    k_out<<<nb_n, 256, 0, stream>>>(h, w2, b2, out, n);
}

// Round 21
// 269.359 us; speedup vs baseline: 1.4311x; 1.0364x over previous
//
#include <hip/hip_runtime.h>

// GCN 2-layer. Round-19: 279us. This round: (1) scan_add deleted (bsum
// folded into slicecur/gathers), (2) k_out fused into gather2 via 8-lane
// shfl feature exchange, (3) gemm1 GROWS=128 + XST=20 pad (36KB LDS -> 4
// blocks/CU, bank-spread reads, no rotation). 12 launches (was 14).

#define NF 512
#define NH 16
#define NRANGE 32
#define NS2 32
#define RS 3125           // nodes per range = 100000/32
#define EB 1024           // edges per bin block
#define GROWS 128         // gemm rows per block
#define GK 16             // gemm k-chunk (double-buffered)
#define XST 20            // xs row stride in floats (80B: aligned + spread)

__device__ __forceinline__ unsigned short f2bf(float f) {
    unsigned u = __float_as_uint(f);
    return (unsigned short)((u + 0x7fff + ((u >> 16) & 1)) >> 16);   // RNE
}
__device__ __forceinline__ float bf2f(unsigned b) {
    return __uint_as_float(b << 16);
}

__global__ __launch_bounds__(256) void k_bincount(const int* __restrict__ dst,
                                                  int* __restrict__ bktcnt,
                                                  int E, int nblk) {
    __shared__ int cnt[NRANGE];
    if (threadIdx.x < NRANGE) cnt[threadIdx.x] = 0;
    __syncthreads();
    int b0 = blockIdx.x * EB;
#pragma unroll
    for (int j = 0; j < 4; ++j) {
        int e = b0 + j * 256 + threadIdx.x;
        if (e < E) atomicAdd(&cnt[dst[e] / RS], 1);
    }
    __syncthreads();
    if (threadIdx.x < NRANGE)
        bktcnt[threadIdx.x * nblk + blockIdx.x] = cnt[threadIdx.x];
}

// exclusive scan (verified rounds 6-19); safe with out==in
__global__ __launch_bounds__(256) void k_scan_block(const int* __restrict__ in,
                                                    int* __restrict__ outp,
                                                    int* __restrict__ bsum, int n) {
    __shared__ int sh[256];
    int t = threadIdx.x, g = blockIdx.x * 256 + t;
    int v = (g < n) ? in[g] : 0;
    sh[t] = v; __syncthreads();
    for (int off = 1; off < 256; off <<= 1) {
        int a = (t >= off) ? sh[t - off] : 0;
        __syncthreads();
        sh[t] += a;
        __syncthreads();
    }
    if (g < n) outp[g] = sh[t] - v;
    if (t == 255) bsum[blockIdx.x] = sh[255];
}

// fused: per-node degree+weight reduction (packed), dinv write, block scan
__global__ __launch_bounds__(256) void k_sumscan(const unsigned* __restrict__ partials,
                                                 int* __restrict__ rowptr,
                                                 int* __restrict__ bsum,
                                                 float* __restrict__ dinv, int n) {
    __shared__ int sh[256];
    int t = threadIdx.x, g = blockIdx.x * 256 + t;
    int v = 0;
    if (g < n) {
        int r = g / RS, b = g - r * RS;
        const unsigned* p = partials + (size_t)(r * NS2) * RS + b;
        unsigned wq = 0;
#pragma unroll
        for (int s = 0; s < NS2; ++s) {
            unsigned pk = p[s * RS];
            v += (int)(pk >> 25);
            wq += pk & 0x1ffffffu;
        }
        dinv[g] = rsqrtf(1.0f + (float)wq * (1.0f / 1024.0f));
    }
    sh[t] = v; __syncthreads();
    for (int off = 1; off < 256; off <<= 1) {
        int a = (t >= off) ? sh[t - off] : 0;
        __syncthreads();
        sh[t] += a;
        __syncthreads();
    }
    if (g < n) rowptr[g] = sh[t] - v;     // block-local; bsum added by consumers
    if (t == 255) bsum[blockIdx.x] = sh[255];
}

__global__ __launch_bounds__(512) void k_scan_tops(int* __restrict__ bsum,
                                                   int* __restrict__ outp,
                                                   int nb, int n) {
    __shared__ int sh[512];
    int t = threadIdx.x;
    int v = (t < nb) ? bsum[t] : 0;
    sh[t] = v; __syncthreads();
    for (int off = 1; off < 512; off <<= 1) {
        int a = (t >= off) ? sh[t - off] : 0;
        __syncthreads();
        sh[t] += a;
        __syncthreads();
    }
    if (t < nb) bsum[t] = sh[t] - v;
    if (t == 511) outp[n] = sh[511];      // absolute total (E)
}

// write each edge once into its bucket; bsum2 offset applied inline
__global__ __launch_bounds__(256) void k_binfill(const int* __restrict__ src,
                                                 const int* __restrict__ dst,
                                                 const float* __restrict__ ew,
                                                 const int* __restrict__ bktcnt,
                                                 const int* __restrict__ bsum2,
                                                 int2* __restrict__ bin,
                                                 int E, int nblk) {
    __shared__ int base[NRANGE];
    if (threadIdx.x < NRANGE) {
        int idx = threadIdx.x * nblk + blockIdx.x;
        base[threadIdx.x] = bktcnt[idx] + bsum2[idx >> 8];
    }
    __syncthreads();
    int b0 = blockIdx.x * EB;
#pragma unroll
    for (int j = 0; j < 4; ++j) {
        int e = b0 + j * 256 + threadIdx.x;
        if (e < E) {
            int d = dst[e];
            int r = d / RS;
            int pos = atomicAdd(&base[r], 1);          // LDS only
            bin[pos] = make_int2((src[e] << 12) | (d - r * RS),
                                 __float_as_int(ew[e]));
        }
    }
}

__device__ __forceinline__ int bkt_start(const int* bktcnt, const int* bsum2,
                                         int r, int nblk, int E) {
    if (r >= NRANGE) return E;
    int idx = r * nblk;
    return bktcnt[idx] + bsum2[idx >> 8];
}

// per-(range, slice) packed LDS histogram: (count<<25) | sum(round(ew*1024))
__global__ __launch_bounds__(256) void k_hist2(const int2* __restrict__ bin,
                                               const int* __restrict__ bktcnt,
                                               const int* __restrict__ bsum2,
                                               unsigned* __restrict__ partials,
                                               int E, int nblk) {
    __shared__ unsigned hist[RS];
    int r = blockIdx.x >> 5, s = blockIdx.x & (NS2 - 1);
    for (int t = threadIdx.x; t < RS; t += 256) hist[t] = 0;
    __syncthreads();
    int b0 = bkt_start(bktcnt, bsum2, r, nblk, E);
    int b1 = bkt_start(bktcnt, bsum2, r + 1, nblk, E);
    int len = b1 - b0, ss = (len + NS2 - 1) / NS2;
    int cs = b0 + s * ss, ce = min(cs + ss, b1);
    for (int j = cs + threadIdx.x; j < ce; j += 256) {
        int2 p2 = bin[j];
        unsigned wq = (unsigned)(__int_as_float(p2.y) * 1024.0f + 0.5f);
        atomicAdd(&hist[p2.x & 4095], (1u << 25) | wq);
    }
    __syncthreads();
    unsigned* pp = partials + (size_t)(r * NS2 + s) * RS;
    for (int t = threadIdx.x; t < RS; t += 256) pp[t] = hist[t];
}

// per-slice packed counts -> exact ABSOLUTE slot starts (bsum folded in)
__global__ __launch_bounds__(256) void k_slicecur(unsigned* __restrict__ partials,
                                                  const int* __restrict__ rowptr,
                                                  const int* __restrict__ bsum, int n) {
    int d = blockIdx.x * 256 + threadIdx.x;
    if (d >= n) return;
    int r = d / RS, b = d - r * RS;
    unsigned* p = partials + (size_t)(r * NS2) * RS + b;
    int run = rowptr[d] + bsum[d >> 8];
#pragma unroll
    for (int s = 0; s < NS2; ++s) {
        int c = (int)(p[s * RS] >> 25);
        p[s * RS] = (unsigned)run;
        run += c;
    }
}

// place edges: csr = (src<<15) | fixed15(dinv[s]*ew*dinv[d])
__global__ __launch_bounds__(256) void k_fill3(const int2* __restrict__ bin,
                                               const int* __restrict__ bktcnt,
                                               const int* __restrict__ bsum2,
                                               const unsigned* __restrict__ partials,
                                               const float* __restrict__ dinv,
                                               unsigned* __restrict__ csr,
                                               int E, int nblk) {
    __shared__ int cur[RS];
    __shared__ float dv[RS];
    int r = blockIdx.x >> 5, s = blockIdx.x & (NS2 - 1);
    const unsigned* cp = partials + (size_t)(r * NS2 + s) * RS;
    for (int t = threadIdx.x; t < RS; t += 256) {
        cur[t] = (int)cp[t];
        dv[t] = dinv[r * RS + t];
    }
    __syncthreads();
    int b0 = bkt_start(bktcnt, bsum2, r, nblk, E);
    int b1 = bkt_start(bktcnt, bsum2, r + 1, nblk, E);
    int len = b1 - b0, ss = (len + NS2 - 1) / NS2;
    int cs = b0 + s * ss, ce = min(cs + ss, b1);
    for (int j = cs + threadIdx.x; j < ce; j += 256) {
        int2 p2 = bin[j];
        int dl = p2.x & 4095;
        int sn = p2.x >> 12;
        float nrm = dinv[sn] * __int_as_float(p2.y) * dv[dl];
        unsigned w15 = (unsigned)(nrm * 32767.0f + 0.5f);
        int pos = atomicAdd(&cur[dl], 1);             // LDS only
        csr[pos] = ((unsigned)sn << 15) | w15;
    }
}

// h = x @ W1: dbuf fp32 xs (XST=20 pad, no rotation) + bf16 W1 (16KB).
// 36KB LDS -> 4 blocks/CU. 128 rows/block, acc[2][4] per thread.
__global__ __launch_bounds__(256) void k_gemm1(const float* __restrict__ x,
                                               const float* __restrict__ w1,
                                               unsigned short* __restrict__ h, int n) {
    __shared__ unsigned wtb[NF * NH / 2];  // 16KB bf16 pairs [k4][f][kk/2]
    __shared__ float xs[2][GROWS * XST];   // 2 x 10KB
    for (int idx = threadIdx.x; idx < NF * NH / 2; idx += 256) {
        int k4 = idx >> 5, rem = idx & 31;
        int f = rem >> 1, kk = (rem & 1) * 2;
        float v0 = w1[(k4 * 4 + kk) * NH + f];
        float v1 = w1[(k4 * 4 + kk + 1) * NH + f];
        wtb[idx] = (unsigned)f2bf(v0) | ((unsigned)f2bf(v1) << 16);
    }
    int rq = threadIdx.x >> 2;             // 0..63
    int fq = threadIdx.x & 3;              // 0..3
    int base = blockIdx.x * GROWS;
    float4 stage[2];
#define LOAD_CHUNK(kc)                                                        \
    _Pragma("unroll")                                                         \
    for (int li = 0; li < 2; ++li) {                                          \
        int idx = li * 256 + threadIdx.x;                                     \
        int row = idx >> 2, c4 = idx & 3;                                     \
        int rg = base + row; if (rg > n - 1) rg = n - 1;                      \
        stage[li] = *(const float4*)(x + (size_t)rg * NF + (kc) * GK + c4 * 4);\
    }
#define WRITE_CHUNK(b)                                                        \
    _Pragma("unroll")                                                         \
    for (int li = 0; li < 2; ++li) {                                          \
        int idx = li * 256 + threadIdx.x;                                     \
        int row = idx >> 2, c4 = idx & 3;                                     \
        float* p = &xs[b][row * XST + c4 * 4];                                \
        p[0] = stage[li].x; p[1] = stage[li].y;                               \
        p[2] = stage[li].z; p[3] = stage[li].w;                               \
    }
    float acc[2][4] = {{0.f}};
    LOAD_CHUNK(0)
    WRITE_CHUNK(0)
    __syncthreads();                       // also covers wtb
    for (int kc = 0; kc < NF / GK; ++kc) {
        if (kc + 1 < NF / GK) { LOAD_CHUNK(kc + 1) }   // in flight over compute
        int b = kc & 1;
#pragma unroll
        for (int k4c = 0; k4c < GK / 4; ++k4c) {
            int k4 = kc * (GK / 4) + k4c;
            float4 wf[4];
#pragma unroll
            for (int c = 0; c < 4; ++c) {
                uint2 u = *(const uint2*)&wtb[k4 * 32 + (fq * 4 + c) * 2];
                wf[c].x = __uint_as_float(u.x << 16);
                wf[c].y = __uint_as_float(u.x & 0xffff0000u);
                wf[c].z = __uint_as_float(u.y << 16);
                wf[c].w = __uint_as_float(u.y & 0xffff0000u);
            }
#pragma unroll
            for (int i = 0; i < 2; ++i) {
                int row = rq * 2 + i;
                float4 xv = *(const float4*)&xs[b][row * XST + k4c * 4];
#pragma unroll
                for (int c = 0; c < 4; ++c) {
                    acc[i][c] = fmaf(xv.x, wf[c].x, acc[i][c]);
                    acc[i][c] = fmaf(xv.y, wf[c].y, acc[i][c]);
                    acc[i][c] = fmaf(xv.z, wf[c].z, acc[i][c]);
                    acc[i][c] = fmaf(xv.w, wf[c].w, acc[i][c]);
                }
            }
        }
        if (kc + 1 < NF / GK) {
            __syncthreads();
            WRITE_CHUNK((kc + 1) & 1)      // vmcnt drain behind compute
            __syncthreads();
        }
    }
#pragma unroll
    for (int i = 0; i < 2; ++i) {
        int r = base + rq * 2 + i;
        if (r < n) {
            ushort4 o;
            o.x = f2bf(acc[i][0]); o.y = f2bf(acc[i][1]);
            o.z = f2bf(acc[i][2]); o.w = f2bf(acc[i][3]);
            *(ushort4*)(h + (size_t)r * NH + fq * 4) = o;
        }
    }
#undef LOAD_CHUNK
#undef WRITE_CHUNK
}

// layer-1 gather + bias/relu; 8 lanes/node, bf16x2; bsum folded into rowptr
__global__ __launch_bounds__(256) void k_gather_relu(const unsigned short* __restrict__ in,
                                                     const float* __restrict__ dinv,
                                                     const int* __restrict__ rowptr,
                                                     const int* __restrict__ bsum,
                                                     const unsigned* __restrict__ csr,
                                                     const float* __restrict__ b1,
                                                     unsigned short* __restrict__ out, int n) {
    int tid = blockIdx.x * 256 + threadIdx.x;
    int d = tid >> 3, l = tid & 7;
    if (d >= n) return;
    float di = dinv[d];
    unsigned self = *(const unsigned*)(in + (size_t)d * NH + 2 * l);
    float a0 = bf2f(self & 0xffffu) * di * di;
    float a1 = bf2f(self >> 16) * di * di;
    int e0 = rowptr[d] + bsum[d >> 8];
    int e1 = (d + 1 < n) ? rowptr[d + 1] + bsum[(d + 1) >> 8] : rowptr[n];
    for (int j = e0; j < e1; ++j) {
        unsigned e = csr[j];
        float nrm = (float)(e & 32767u) * (1.0f / 32767.0f);
        unsigned pr = *(const unsigned*)(in + (size_t)(e >> 15) * NH + 2 * l);
        a0 = fmaf(bf2f(pr & 0xffffu), nrm, a0);
        a1 = fmaf(bf2f(pr >> 16), nrm, a1);
    }
    a0 = fmaxf(a0 + b1[2 * l], 0.0f);
    a1 = fmaxf(a1 + b1[2 * l + 1], 0.0f);
    unsigned pk = (unsigned)f2bf(a0) | ((unsigned)f2bf(a1) << 16);
    *(unsigned*)(out + (size_t)d * NH + 2 * l) = pk;
}

// layer-2 gather FUSED with W2 + b2 + log_softmax (k_out eliminated).
// 8 lanes/node: shfl-exchange 16 features, each lane computes 5 classes.
__global__ __launch_bounds__(256) void k_gather_out(const unsigned short* __restrict__ in,
                                                    const float* __restrict__ dinv,
                                                    const int* __restrict__ rowptr,
                                                    const int* __restrict__ bsum,
                                                    const unsigned* __restrict__ csr,
                                                    const float* __restrict__ w2,
                                                    const float* __restrict__ b2,
                                                    float* __restrict__ out, int n) {
    __shared__ float w2s[NH * 40];
    __shared__ float b2s[40];
    for (int t = threadIdx.x; t < NH * 40; t += 256) w2s[t] = w2[t];
    if (threadIdx.x < 40) b2s[threadIdx.x] = b2[threadIdx.x];
    __syncthreads();
    int tid = blockIdx.x * 256 + threadIdx.x;
    int d = tid >> 3, l = tid & 7;
    if (d >= n) return;
    float di = dinv[d];
    unsigned self = *(const unsigned*)(in + (size_t)d * NH + 2 * l);
    float a0 = bf2f(self & 0xffffu) * di * di;
    float a1 = bf2f(self >> 16) * di * di;
    int e0 = rowptr[d] + bsum[d >> 8];
    int e1 = (d + 1 < n) ? rowptr[d + 1] + bsum[(d + 1) >> 8] : rowptr[n];
    for (int j = e0; j < e1; ++j) {
        unsigned e = csr[j];
        float nrm = (float)(e & 32767u) * (1.0f / 32767.0f);
        unsigned pr = *(const unsigned*)(in + (size_t)(e >> 15) * NH + 2 * l);
        a0 = fmaf(bf2f(pr & 0xffffu), nrm, a0);
        a1 = fmaf(bf2f(pr >> 16), nrm, a1);
    }
    // exchange 16 features across the node's 8 lanes
    float v[NH];
#pragma unroll
    for (int m = 0; m < 8; ++m) {
        v[2 * m] = __shfl(a0, m, 8);
        v[2 * m + 1] = __shfl(a1, m, 8);
    }
    // each lane computes classes c = l*5 .. l*5+4
    float z[5];
#pragma unroll
    for (int j5 = 0; j5 < 5; ++j5) {
        int c = l * 5 + j5;
        float a = b2s[c];
#pragma unroll
        for (int ff = 0; ff < NH; ++ff) a = fmaf(v[ff], w2s[ff * 40 + c], a);
        z[j5] = a;
    }
    float mx = z[0];
#pragma unroll
    for (int j5 = 1; j5 < 5; ++j5) mx = fmaxf(mx, z[j5]);
#pragma unroll
    for (int off = 4; off; off >>= 1) mx = fmaxf(mx, __shfl_xor(mx, off, 8));
    float sum = 0.0f;
#pragma unroll
    for (int j5 = 0; j5 < 5; ++j5) sum += expf(z[j5] - mx);
#pragma unroll
    for (int off = 4; off; off >>= 1) sum += __shfl_xor(sum, off, 8);
    float ls = mx + logf(sum);
    float* op = out + (size_t)d * 40 + l * 5;
#pragma unroll
    for (int j5 = 0; j5 < 5; ++j5) op[j5] = z[j5] - ls;
}

extern "C" void kernel_launch(void* const* d_in, const int* in_sizes, int n_in,
                              void* d_out, int out_size, void* d_ws, size_t ws_size,
                              hipStream_t stream) {
    const float* x  = (const float*)d_in[0];
    const int*   ei = (const int*)d_in[1];
    const float* ew = (const float*)d_in[2];
    const float* w1 = (const float*)d_in[3];
    const float* b1 = (const float*)d_in[4];
    const float* w2 = (const float*)d_in[5];
    const float* b2 = (const float*)d_in[6];
    float* out = (float*)d_out;

    int n = in_sizes[0] / NF;      // 100000 (= NRANGE*RS)
    int E = in_sizes[2];           // 3200000
    const int* src = ei;
    const int* dst = ei + E;

    float*          ws       = (float*)d_ws;
    float*          dinv     = ws;                        // n
    int*            bsum     = (int*)(ws + 200000);       // 1024
    int*            rowptr   = (int*)(ws + 201024);       // n+1
    int*            bsum2    = (int*)(ws + 301056);       // 1024
    int*            bktcnt   = (int*)(ws + 302080);       // 100032
    unsigned*       partials = (unsigned*)(ws + 402112);  // 3.2M packed
    unsigned*       csr      = (unsigned*)(ws + 6802112); // E
    int2*           bin      = (int2*)(ws + 10002112);    // 2E, dead after fill3
    unsigned short* h        = (unsigned short*)(ws + 10002112);  // overlays bin
    unsigned short* o1       = (unsigned short*)(ws + 10802112);  // overlays bin

    int nblk  = (E + EB - 1) / EB;              // 3125 bin blocks
    int ncnt  = NRANGE * nblk;                  // 100000 counts
    int nb_c  = (ncnt + 255) / 256;             // 391
    int nb_n  = (n + 255) / 256;                // 391
    int nb_g8 = (n * 8 + 255) / 256;            // 3125 gather blocks
    int nb_g  = (n + GROWS - 1) / GROWS;        // 782 gemm blocks

    // 1) bin counts + bases
    k_bincount<<<nblk, 256, 0, stream>>>(dst, bktcnt, E, nblk);
    k_scan_block<<<nb_c, 256, 0, stream>>>(bktcnt, bktcnt, bsum2, ncnt);
    k_scan_tops<<<1, 512, 0, stream>>>(bsum2, bktcnt, nb_c, ncnt);
    // 2) bin edges (one int2 scatter per edge)
    k_binfill<<<nblk, 256, 0, stream>>>(src, dst, ew, bktcnt, bsum2, bin, E, nblk);
    // 3) packed hist -> dinv+rowptr -> exact 4B CSR with baked nrm
    k_hist2<<<NRANGE * NS2, 256, 0, stream>>>(bin, bktcnt, bsum2, partials, E, nblk);
    k_sumscan<<<nb_n, 256, 0, stream>>>(partials, rowptr, bsum, dinv, n);
    k_scan_tops<<<1, 512, 0, stream>>>(bsum, rowptr, nb_n, n);
    k_slicecur<<<nb_n, 256, 0, stream>>>(partials, rowptr, bsum, n);
    k_fill3<<<NRANGE * NS2, 256, 0, stream>>>(bin, bktcnt, bsum2, partials,
                                              dinv, csr, E, nblk);
    // 4) GCN pipeline (bf16 h/o1; k_out fused into gather2)
    k_gemm1<<<nb_g, 256, 0, stream>>>(x, w1, h, n);
    k_gather_relu<<<nb_g8, 256, 0, stream>>>(h, dinv, rowptr, bsum, csr, b1, o1, n);
    k_gather_out<<<nb_g8, 256, 0, stream>>>(o1, dinv, rowptr, bsum, csr, w2, b2, out, n);
}

// Round 24
// 247.700 us; speedup vs baseline: 1.5562x; 1.0874x over previous
//
#include <hip/hip_runtime.h>

// GCN 2-layer. Round-21: 269us. Gathers are the latency suspects: avg
// degree 32 = 32-iteration serial loop per node. This round: 16 lanes/node
// (2 edge-halves x 8 feature-lanes, interleaved j+=2), one shfl_xor(8)
// combine -> serial loop halved to ~16 iters. unroll-2 for load ILP.

#define NF 512
#define NH 16
#define NRANGE 32
#define NS2 32
#define RS 3125           // nodes per range = 100000/32
#define EB 1024           // edges per bin block
#define GROWS 128         // gemm rows per block
#define GK 16             // gemm k-chunk (double-buffered)
#define XST 20            // xs row stride in floats (80B: aligned + spread)

__device__ __forceinline__ unsigned short f2bf(float f) {
    unsigned u = __float_as_uint(f);
    return (unsigned short)((u + 0x7fff + ((u >> 16) & 1)) >> 16);   // RNE
}
__device__ __forceinline__ float bf2f(unsigned b) {
    return __uint_as_float(b << 16);
}

__global__ __launch_bounds__(256) void k_bincount(const int* __restrict__ dst,
                                                  int* __restrict__ bktcnt,
                                                  int E, int nblk) {
    __shared__ int cnt[NRANGE];
    if (threadIdx.x < NRANGE) cnt[threadIdx.x] = 0;
    __syncthreads();
    int b0 = blockIdx.x * EB;
#pragma unroll
    for (int j = 0; j < 4; ++j) {
        int e = b0 + j * 256 + threadIdx.x;
        if (e < E) atomicAdd(&cnt[dst[e] / RS], 1);
    }
    __syncthreads();
    if (threadIdx.x < NRANGE)
        bktcnt[threadIdx.x * nblk + blockIdx.x] = cnt[threadIdx.x];
}

// exclusive scan (verified rounds 6-21); safe with out==in
__global__ __launch_bounds__(256) void k_scan_block(const int* __restrict__ in,
                                                    int* __restrict__ outp,
                                                    int* __restrict__ bsum, int n) {
    __shared__ int sh[256];
    int t = threadIdx.x, g = blockIdx.x * 256 + t;
    int v = (g < n) ? in[g] : 0;
    sh[t] = v; __syncthreads();
    for (int off = 1; off < 256; off <<= 1) {
        int a = (t >= off) ? sh[t - off] : 0;
        __syncthreads();
        sh[t] += a;
        __syncthreads();
    }
    if (g < n) outp[g] = sh[t] - v;
    if (t == 255) bsum[blockIdx.x] = sh[255];
}

// fused: per-node degree+weight reduction (packed), dinv write, block scan
__global__ __launch_bounds__(256) void k_sumscan(const unsigned* __restrict__ partials,
                                                 int* __restrict__ rowptr,
                                                 int* __restrict__ bsum,
                                                 float* __restrict__ dinv, int n) {
    __shared__ int sh[256];
    int t = threadIdx.x, g = blockIdx.x * 256 + t;
    int v = 0;
    if (g < n) {
        int r = g / RS, b = g - r * RS;
        const unsigned* p = partials + (size_t)(r * NS2) * RS + b;
        unsigned wq = 0;
#pragma unroll
        for (int s = 0; s < NS2; ++s) {
            unsigned pk = p[s * RS];
            v += (int)(pk >> 25);
            wq += pk & 0x1ffffffu;
        }
        dinv[g] = rsqrtf(1.0f + (float)wq * (1.0f / 1024.0f));
    }
    sh[t] = v; __syncthreads();
    for (int off = 1; off < 256; off <<= 1) {
        int a = (t >= off) ? sh[t - off] : 0;
        __syncthreads();
        sh[t] += a;
        __syncthreads();
    }
    if (g < n) rowptr[g] = sh[t] - v;     // block-local; bsum added by consumers
    if (t == 255) bsum[blockIdx.x] = sh[255];
}

__global__ __launch_bounds__(512) void k_scan_tops(int* __restrict__ bsum,
                                                   int* __restrict__ outp,
                                                   int nb, int n) {
    __shared__ int sh[512];
    int t = threadIdx.x;
    int v = (t < nb) ? bsum[t] : 0;
    sh[t] = v; __syncthreads();
    for (int off = 1; off < 512; off <<= 1) {
        int a = (t >= off) ? sh[t - off] : 0;
        __syncthreads();
        sh[t] += a;
        __syncthreads();
    }
    if (t < nb) bsum[t] = sh[t] - v;
    if (t == 511) outp[n] = sh[511];      // absolute total (E)
}

// write each edge once into its bucket; bsum2 offset applied inline
__global__ __launch_bounds__(256) void k_binfill(const int* __restrict__ src,
                                                 const int* __restrict__ dst,
                                                 const float* __restrict__ ew,
                                                 const int* __restrict__ bktcnt,
                                                 const int* __restrict__ bsum2,
                                                 int2* __restrict__ bin,
                                                 int E, int nblk) {
    __shared__ int base[NRANGE];
    if (threadIdx.x < NRANGE) {
        int idx = threadIdx.x * nblk + blockIdx.x;
        base[threadIdx.x] = bktcnt[idx] + bsum2[idx >> 8];
    }
    __syncthreads();
    int b0 = blockIdx.x * EB;
#pragma unroll
    for (int j = 0; j < 4; ++j) {
        int e = b0 + j * 256 + threadIdx.x;
        if (e < E) {
            int d = dst[e];
            int r = d / RS;
            int pos = atomicAdd(&base[r], 1);          // LDS only
            bin[pos] = make_int2((src[e] << 12) | (d - r * RS),
                                 __float_as_int(ew[e]));
        }
    }
}

__device__ __forceinline__ int bkt_start(const int* bktcnt, const int* bsum2,
                                         int r, int nblk, int E) {
    if (r >= NRANGE) return E;
    int idx = r * nblk;
    return bktcnt[idx] + bsum2[idx >> 8];
}

// per-(range, slice) packed LDS histogram: (count<<25) | sum(round(ew*1024))
__global__ __launch_bounds__(256) void k_hist2(const int2* __restrict__ bin,
                                               const int* __restrict__ bktcnt,
                                               const int* __restrict__ bsum2,
                                               unsigned* __restrict__ partials,
                                               int E, int nblk) {
    __shared__ unsigned hist[RS];
    int r = blockIdx.x >> 5, s = blockIdx.x & (NS2 - 1);
    for (int t = threadIdx.x; t < RS; t += 256) hist[t] = 0;
    __syncthreads();
    int b0 = bkt_start(bktcnt, bsum2, r, nblk, E);
    int b1 = bkt_start(bktcnt, bsum2, r + 1, nblk, E);
    int len = b1 - b0, ss = (len + NS2 - 1) / NS2;
    int cs = b0 + s * ss, ce = min(cs + ss, b1);
    for (int j = cs + threadIdx.x; j < ce; j += 256) {
        int2 p2 = bin[j];
        unsigned wq = (unsigned)(__int_as_float(p2.y) * 1024.0f + 0.5f);
        atomicAdd(&hist[p2.x & 4095], (1u << 25) | wq);
    }
    __syncthreads();
    unsigned* pp = partials + (size_t)(r * NS2 + s) * RS;
    for (int t = threadIdx.x; t < RS; t += 256) pp[t] = hist[t];
}

// per-slice packed counts -> exact ABSOLUTE slot starts (bsum folded in)
__global__ __launch_bounds__(256) void k_slicecur(unsigned* __restrict__ partials,
                                                  const int* __restrict__ rowptr,
                                                  const int* __restrict__ bsum, int n) {
    int d = blockIdx.x * 256 + threadIdx.x;
    if (d >= n) return;
    int r = d / RS, b = d - r * RS;
    unsigned* p = partials + (size_t)(r * NS2) * RS + b;
    int run = rowptr[d] + bsum[d >> 8];
#pragma unroll
    for (int s = 0; s < NS2; ++s) {
        int c = (int)(p[s * RS] >> 25);
        p[s * RS] = (unsigned)run;
        run += c;
    }
}

// place edges: csr = (src<<15) | fixed15(dinv[s]*ew*dinv[d])
__global__ __launch_bounds__(256) void k_fill3(const int2* __restrict__ bin,
                                               const int* __restrict__ bktcnt,
                                               const int* __restrict__ bsum2,
                                               const unsigned* __restrict__ partials,
                                               const float* __restrict__ dinv,
                                               unsigned* __restrict__ csr,
                                               int E, int nblk) {
    __shared__ int cur[RS];
    __shared__ float dv[RS];
    int r = blockIdx.x >> 5, s = blockIdx.x & (NS2 - 1);
    const unsigned* cp = partials + (size_t)(r * NS2 + s) * RS;
    for (int t = threadIdx.x; t < RS; t += 256) {
        cur[t] = (int)cp[t];
        dv[t] = dinv[r * RS + t];
    }
    __syncthreads();
    int b0 = bkt_start(bktcnt, bsum2, r, nblk, E);
    int b1 = bkt_start(bktcnt, bsum2, r + 1, nblk, E);
    int len = b1 - b0, ss = (len + NS2 - 1) / NS2;
    int cs = b0 + s * ss, ce = min(cs + ss, b1);
    for (int j = cs + threadIdx.x; j < ce; j += 256) {
        int2 p2 = bin[j];
        int dl = p2.x & 4095;
        int sn = p2.x >> 12;
        float nrm = dinv[sn] * __int_as_float(p2.y) * dv[dl];
        unsigned w15 = (unsigned)(nrm * 32767.0f + 0.5f);
        int pos = atomicAdd(&cur[dl], 1);             // LDS only
        csr[pos] = ((unsigned)sn << 15) | w15;
    }
}

// h = x @ W1: dbuf fp32 xs (XST=20) + bf16 W1 (16KB). 36KB -> 4 blocks/CU.
__global__ __launch_bounds__(256) void k_gemm1(const float* __restrict__ x,
                                               const float* __restrict__ w1,
                                               unsigned short* __restrict__ h, int n) {
    __shared__ unsigned wtb[NF * NH / 2];  // 16KB bf16 pairs [k4][f][kk/2]
    __shared__ float xs[2][GROWS * XST];   // 2 x 10KB
    for (int idx = threadIdx.x; idx < NF * NH / 2; idx += 256) {
        int k4 = idx >> 5, rem = idx & 31;
        int f = rem >> 1, kk = (rem & 1) * 2;
        float v0 = w1[(k4 * 4 + kk) * NH + f];
        float v1 = w1[(k4 * 4 + kk + 1) * NH + f];
        wtb[idx] = (unsigned)f2bf(v0) | ((unsigned)f2bf(v1) << 16);
    }
    int rq = threadIdx.x >> 2;             // 0..63
    int fq = threadIdx.x & 3;              // 0..3
    int base = blockIdx.x * GROWS;
    float4 stage[2];
#define LOAD_CHUNK(kc)                                                        \
    _Pragma("unroll")                                                         \
    for (int li = 0; li < 2; ++li) {                                          \
        int idx = li * 256 + threadIdx.x;                                     \
        int row = idx >> 2, c4 = idx & 3;                                     \
        int rg = base + row; if (rg > n - 1) rg = n - 1;                      \
        stage[li] = *(const float4*)(x + (size_t)rg * NF + (kc) * GK + c4 * 4);\
    }
#define WRITE_CHUNK(b)                                                        \
    _Pragma("unroll")                                                         \
    for (int li = 0; li < 2; ++li) {                                          \
        int idx = li * 256 + threadIdx.x;                                     \
        int row = idx >> 2, c4 = idx & 3;                                     \
        float* p = &xs[b][row * XST + c4 * 4];                                \
        p[0] = stage[li].x; p[1] = stage[li].y;                               \
        p[2] = stage[li].z; p[3] = stage[li].w;                               \
    }
    float acc[2][4] = {{0.f}};
    LOAD_CHUNK(0)
    WRITE_CHUNK(0)
    __syncthreads();                       // also covers wtb
    for (int kc = 0; kc < NF / GK; ++kc) {
        if (kc + 1 < NF / GK) { LOAD_CHUNK(kc + 1) }   // in flight over compute
        int b = kc & 1;
#pragma unroll
        for (int k4c = 0; k4c < GK / 4; ++k4c) {
            int k4 = kc * (GK / 4) + k4c;
            float4 wf[4];
#pragma unroll
            for (int c = 0; c < 4; ++c) {
                uint2 u = *(const uint2*)&wtb[k4 * 32 + (fq * 4 + c) * 2];
                wf[c].x = __uint_as_float(u.x << 16);
                wf[c].y = __uint_as_float(u.x & 0xffff0000u);
                wf[c].z = __uint_as_float(u.y << 16);
                wf[c].w = __uint_as_float(u.y & 0xffff0000u);
            }
#pragma unroll
            for (int i = 0; i < 2; ++i) {
                int row = rq * 2 + i;
                float4 xv = *(const float4*)&xs[b][row * XST + k4c * 4];
#pragma unroll
                for (int c = 0; c < 4; ++c) {
                    acc[i][c] = fmaf(xv.x, wf[c].x, acc[i][c]);
                    acc[i][c] = fmaf(xv.y, wf[c].y, acc[i][c]);
                    acc[i][c] = fmaf(xv.z, wf[c].z, acc[i][c]);
                    acc[i][c] = fmaf(xv.w, wf[c].w, acc[i][c]);
                }
            }
        }
        if (kc + 1 < NF / GK) {
            __syncthreads();
            WRITE_CHUNK((kc + 1) & 1)      // vmcnt drain behind compute
            __syncthreads();
        }
    }
#pragma unroll
    for (int i = 0; i < 2; ++i) {
        int r = base + rq * 2 + i;
        if (r < n) {
            ushort4 o;
            o.x = f2bf(acc[i][0]); o.y = f2bf(acc[i][1]);
            o.z = f2bf(acc[i][2]); o.w = f2bf(acc[i][3]);
            *(ushort4*)(h + (size_t)r * NH + fq * 4) = o;
        }
    }
#undef LOAD_CHUNK
#undef WRITE_CHUNK
}

// layer-1 gather + bias/relu; 16 lanes/node = 2 edge-halves x 8 f-lanes
__global__ __launch_bounds__(256) void k_gather_relu(const unsigned short* __restrict__ in,
                                                     const float* __restrict__ dinv,
                                                     const int* __restrict__ rowptr,
                                                     const int* __restrict__ bsum,
                                                     const unsigned* __restrict__ csr,
                                                     const float* __restrict__ b1,
                                                     unsigned short* __restrict__ out, int n) {
    int tid = blockIdx.x * 256 + threadIdx.x;
    int d = tid >> 4, l = tid & 7, hf = (tid >> 3) & 1;
    if (d >= n) return;
    float di = dinv[d];
    float a0 = 0.0f, a1 = 0.0f;
    if (!hf) {
        unsigned self = *(const unsigned*)(in + (size_t)d * NH + 2 * l);
        a0 = bf2f(self & 0xffffu) * di * di;
        a1 = bf2f(self >> 16) * di * di;
    }
    int e0 = rowptr[d] + bsum[d >> 8];
    int e1 = (d + 1 < n) ? rowptr[d + 1] + bsum[(d + 1) >> 8] : rowptr[n];
#pragma unroll 2
    for (int j = e0 + hf; j < e1; j += 2) {
        unsigned e = csr[j];
        float nrm = (float)(e & 32767u) * (1.0f / 32767.0f);
        unsigned pr = *(const unsigned*)(in + (size_t)(e >> 15) * NH + 2 * l);
        a0 = fmaf(bf2f(pr & 0xffffu), nrm, a0);
        a1 = fmaf(bf2f(pr >> 16), nrm, a1);
    }
    a0 += __shfl_xor(a0, 8, 16);           // combine halves
    a1 += __shfl_xor(a1, 8, 16);
    if (!hf) {
        a0 = fmaxf(a0 + b1[2 * l], 0.0f);
        a1 = fmaxf(a1 + b1[2 * l + 1], 0.0f);
        unsigned pk = (unsigned)f2bf(a0) | ((unsigned)f2bf(a1) << 16);
        *(unsigned*)(out + (size_t)d * NH + 2 * l) = pk;
    }
}

// layer-2 gather + W2 + b2 + log_softmax; 16 lanes/node, halves combined,
// class math on lower 8 lanes (upper duplicates harmlessly).
__global__ __launch_bounds__(256) void k_gather_out(const unsigned short* __restrict__ in,
                                                    const float* __restrict__ dinv,
                                                    const int* __restrict__ rowptr,
                                                    const int* __restrict__ bsum,
                                                    const unsigned* __restrict__ csr,
                                                    const float* __restrict__ w2,
                                                    const float* __restrict__ b2,
                                                    float* __restrict__ out, int n) {
    __shared__ float w2s[NH * 40];
    __shared__ float b2s[40];
    for (int t = threadIdx.x; t < NH * 40; t += 256) w2s[t] = w2[t];
    if (threadIdx.x < 40) b2s[threadIdx.x] = b2[threadIdx.x];
    __syncthreads();
    int tid = blockIdx.x * 256 + threadIdx.x;
    int d = tid >> 4, l = tid & 7, hf = (tid >> 3) & 1;
    if (d >= n) return;
    float di = dinv[d];
    float a0 = 0.0f, a1 = 0.0f;
    if (!hf) {
        unsigned self = *(const unsigned*)(in + (size_t)d * NH + 2 * l);
        a0 = bf2f(self & 0xffffu) * di * di;
        a1 = bf2f(self >> 16) * di * di;
    }
    int e0 = rowptr[d] + bsum[d >> 8];
    int e1 = (d + 1 < n) ? rowptr[d + 1] + bsum[(d + 1) >> 8] : rowptr[n];
#pragma unroll 2
    for (int j = e0 + hf; j < e1; j += 2) {
        unsigned e = csr[j];
        float nrm = (float)(e & 32767u) * (1.0f / 32767.0f);
        unsigned pr = *(const unsigned*)(in + (size_t)(e >> 15) * NH + 2 * l);
        a0 = fmaf(bf2f(pr & 0xffffu), nrm, a0);
        a1 = fmaf(bf2f(pr >> 16), nrm, a1);
    }
    a0 += __shfl_xor(a0, 8, 16);           // both halves now hold full sums
    a1 += __shfl_xor(a1, 8, 16);
    // exchange 16 features within the 16-lane group (lane m and m+8 match)
    float v[NH];
#pragma unroll
    for (int m = 0; m < 8; ++m) {
        v[2 * m] = __shfl(a0, m, 16);
        v[2 * m + 1] = __shfl(a1, m, 16);
    }
    float z[5];
#pragma unroll
    for (int j5 = 0; j5 < 5; ++j5) {
        int c = l * 5 + j5;
        float a = b2s[c];
#pragma unroll
        for (int ff = 0; ff < NH; ++ff) a = fmaf(v[ff], w2s[ff * 40 + c], a);
        z[j5] = a;
    }
    float mx = z[0];
#pragma unroll
    for (int j5 = 1; j5 < 5; ++j5) mx = fmaxf(mx, z[j5]);
#pragma unroll
    for (int off = 4; off; off >>= 1) mx = fmaxf(mx, __shfl_xor(mx, off, 8));
    float sum = 0.0f;
#pragma unroll
    for (int j5 = 0; j5 < 5; ++j5) sum += expf(z[j5] - mx);
#pragma unroll
    for (int off = 4; off; off >>= 1) sum += __shfl_xor(sum, off, 8);
    float ls = mx + logf(sum);
    if (!hf) {
        float* op = out + (size_t)d * 40 + l * 5;
#pragma unroll
        for (int j5 = 0; j5 < 5; ++j5) op[j5] = z[j5] - ls;
    }
}

extern "C" void kernel_launch(void* const* d_in, const int* in_sizes, int n_in,
                              void* d_out, int out_size, void* d_ws, size_t ws_size,
                              hipStream_t stream) {
    const float* x  = (const float*)d_in[0];
    const int*   ei = (const int*)d_in[1];
    const float* ew = (const float*)d_in[2];
    const float* w1 = (const float*)d_in[3];
    const float* b1 = (const float*)d_in[4];
    const float* w2 = (const float*)d_in[5];
    const float* b2 = (const float*)d_in[6];
    float* out = (float*)d_out;

    int n = in_sizes[0] / NF;      // 100000 (= NRANGE*RS)
    int E = in_sizes[2];           // 3200000
    const int* src = ei;
    const int* dst = ei + E;

    float*          ws       = (float*)d_ws;
    float*          dinv     = ws;                        // n
    int*            bsum     = (int*)(ws + 200000);       // 1024
    int*            rowptr   = (int*)(ws + 201024);       // n+1
    int*            bsum2    = (int*)(ws + 301056);       // 1024
    int*            bktcnt   = (int*)(ws + 302080);       // 100032
    unsigned*       partials = (unsigned*)(ws + 402112);  // 3.2M packed
    unsigned*       csr      = (unsigned*)(ws + 6802112); // E
    int2*           bin      = (int2*)(ws + 10002112);    // 2E, dead after fill3
    unsigned short* h        = (unsigned short*)(ws + 10002112);  // overlays bin
    unsigned short* o1       = (unsigned short*)(ws + 10802112);  // overlays bin

    int nblk   = (E + EB - 1) / EB;             // 3125 bin blocks
    int ncnt   = NRANGE * nblk;                 // 100000 counts
    int nb_c   = (ncnt + 255) / 256;            // 391
    int nb_n   = (n + 255) / 256;               // 391
    int nb_g16 = (n * 16 + 255) / 256;          // 6250 gather blocks
    int nb_g   = (n + GROWS - 1) / GROWS;       // 782 gemm blocks

    // 1) bin counts + bases
    k_bincount<<<nblk, 256, 0, stream>>>(dst, bktcnt, E, nblk);
    k_scan_block<<<nb_c, 256, 0, stream>>>(bktcnt, bktcnt, bsum2, ncnt);
    k_scan_tops<<<1, 512, 0, stream>>>(bsum2, bktcnt, nb_c, ncnt);
    // 2) bin edges (one int2 scatter per edge)
    k_binfill<<<nblk, 256, 0, stream>>>(src, dst, ew, bktcnt, bsum2, bin, E, nblk);
    // 3) packed hist -> dinv+rowptr -> exact 4B CSR with baked nrm
    k_hist2<<<NRANGE * NS2, 256, 0, stream>>>(bin, bktcnt, bsum2, partials, E, nblk);
    k_sumscan<<<nb_n, 256, 0, stream>>>(partials, rowptr, bsum, dinv, n);
    k_scan_tops<<<1, 512, 0, stream>>>(bsum, rowptr, nb_n, n);
    k_slicecur<<<nb_n, 256, 0, stream>>>(partials, rowptr, bsum, n);
    k_fill3<<<NRANGE * NS2, 256, 0, stream>>>(bin, bktcnt, bsum2, partials,
                                              dinv, csr, E, nblk);
    // 4) GCN pipeline (bf16 h/o1)
    k_gemm1<<<nb_g, 256, 0, stream>>>(x, w1, h, n);
    k_gather_relu<<<nb_g16, 256, 0, stream>>>(h, dinv, rowptr, bsum, csr, b1, o1, n);
    k_gather_out<<<nb_g16, 256, 0, stream>>>(o1, dinv, rowptr, bsum, csr, w2, b2, out, n);
}